// Round 11
// baseline (978.225 us; speedup 1.0000x reference)
//
#include <hip/hip_runtime.h>
#include <math.h>

#define NB 128      // B
#define NT 12       // T
#define NNODE 207   // N
#define NF 14       // F
#define NH 128      // H
#define ROWS (NB*NNODE)      // 26496
#define BTN (NB*NT*NNODE)    // 317952
#define G3 (3*NH)            // 384
#define LSTR 208             // padded Laplacian row stride
#define RG (ROWS/32)         // 828 row-groups of 32

typedef __attribute__((ext_vector_type(8))) short short8;   // 8 bf16 = 4 VGPR
typedef __attribute__((ext_vector_type(4))) float accf4;    // MFMA C/D

#define MFMA16 __builtin_amdgcn_mfma_f32_16x16x32_bf16

__device__ __forceinline__ float sigf(float x){ return 1.0f/(1.0f+__expf(-x)); }
__device__ __forceinline__ unsigned short f2b(float f){
  unsigned int u = __float_as_uint(f);
  return (unsigned short)((u + 0x7FFFu + ((u>>16)&1u)) >> 16);
}
__device__ __forceinline__ float b2f(unsigned short h){
  return __uint_as_float(((unsigned int)h) << 16);
}
// split-bf16 3-term product: hi*hi + lo*hi + hi*lo (lo*lo ~2^-16, negligible)
__device__ __forceinline__ void mm3(short8 ah, short8 al, short8 bh, short8 bl, accf4& acc){
  acc = MFMA16(ah, bh, acc, 0,0,0);
  acc = MFMA16(al, bh, acc, 0,0,0);
  acc = MFMA16(ah, bl, acc, 0,0,0);
}

__global__ __launch_bounds__(256) void k_sentinel(float* __restrict__ out, int n){
  int i = blockIdx.x*256 + threadIdx.x;
  if (i < n) out[i] = 12345.0f;
}

// ---- weight prep (fragment-layout bf16 hi/lo) ----
#define NW_ENC (7*24*64*8)   // 86016
#define NW_DEC (4*24*64*8)   // 49152
#define SH_TOTAL (2*NW_ENC + 2*NW_DEC)
#define FWT_TOTAL (32*384 + 384)
#define PREP_TOTAL (NW_ENC + NW_DEC + 32*384 + 384)
__global__ __launch_bounds__(256) void k_prep(const float* __restrict__ ewih,
    const float* __restrict__ ewhh, const float* __restrict__ dwih,
    const float* __restrict__ dwhh, short* __restrict__ ws, float* __restrict__ wf){
  int i = blockIdx.x*256 + threadIdx.x;
  if (i < NW_ENC){
    int e = i & 7, lane = (i>>3) & 63, ct = (i>>9) % 24, ks = i / 12288;
    int k = ks*32 + (lane>>4)*8 + e;
    int col = ct*16 + (lane&15);
    float wv = (k < 65) ? ewih[col*65 + k] : ((k < 96) ? 0.f : ewhh[col*128 + (k-96)]);
    unsigned short hi = f2b(wv);
    ws[i] = (short)hi;
    ws[NW_ENC + i] = (short)f2b(wv - b2f(hi));
  } else if (i < NW_ENC + NW_DEC){
    int j = i - NW_ENC;
    int e = j & 7, lane = (j>>3) & 63, ct = (j>>9) % 24, ks = j / 12288;
    int k = ks*32 + (lane>>4)*8 + e;
    int col = ct*16 + (lane&15);
    float wv = dwhh[col*128 + k];
    unsigned short hi = f2b(wv);
    ws[2*NW_ENC + j] = (short)hi;
    ws[2*NW_ENC + NW_DEC + j] = (short)f2b(wv - b2f(hi));
  } else if (i < NW_ENC + NW_DEC + 32*384){
    int j = i - (NW_ENC + NW_DEC); int k = j/384, n = j%384;
    wf[j] = dwih[n*33 + 1 + k];
  } else if (i < PREP_TOTAL){
    int n = i - (NW_ENC + NW_DEC + 32*384);
    wf[32*384 + n] = dwih[n*33];
  }
}

// emb = tanh(state * fc_w + fc_b)
__global__ __launch_bounds__(256) void k_emb(const float* __restrict__ x,
    const float* __restrict__ w, const float* __restrict__ b, float* __restrict__ emb){
  int idx = blockIdx.x*256 + threadIdx.x;
  if (idx >= ROWS*16) return;
  int j = idx & 15, row = idx >> 4;
  int bb = row / NNODE, n = row % NNODE;
  float s = x[((bb*NT + (NT-1))*NNODE + n)*NF];
  emb[idx] = tanhf(s*w[j] + b[j]);
}

// wave-per-row adjacency
__global__ __launch_bounds__(256) void k_adj(const float* __restrict__ emb,
    const float* __restrict__ Aph, const float* __restrict__ alp,
    float* __restrict__ Abuf, float* __restrict__ rsum){
  int wid = threadIdx.x >> 6, lane = threadIdx.x & 63;
  int row = blockIdx.x*4 + wid;
  int bb = row / NNODE, n = row % NNODE;
  const float4* er = (const float4*)(emb + (size_t)row*16);
  float4 e0 = er[0], e1 = er[1], e2 = er[2], e3 = er[3];
  float d[4];
  #pragma unroll
  for (int q=0;q<4;++q){
    int m = lane + q*64;
    float dd = -1.f;
    if (m < NNODE){
      const float4* em = (const float4*)(emb + (size_t)(bb*NNODE+m)*16);
      float4 m0 = em[0], m1 = em[1], m2 = em[2], m3 = em[3];
      dd = e0.x*m0.x + e0.y*m0.y + e0.z*m0.z + e0.w*m0.w
         + e1.x*m1.x + e1.y*m1.y + e1.z*m1.z + e1.w*m1.w
         + e2.x*m2.x + e2.y*m2.y + e2.z*m2.z + e2.w*m2.w
         + e3.x*m3.x + e3.y*m3.y + e3.z*m3.z + e3.w*m3.w;
      dd = dd > 0.f ? dd : 0.f;
    }
    d[q] = dd;
  }
  int km = 0;
  float vmax = 0.f;
  for (int it=0; it<10; ++it){
    float v = -1.f; int mi = 1<<20;
    #pragma unroll
    for (int q=0;q<4;++q){
      if (d[q] >= 0.f && !((km>>q)&1) && d[q] > v){ v = d[q]; mi = lane + q*64; }
    }
    #pragma unroll
    for (int off=1; off<64; off<<=1){
      float v2 = __shfl_xor(v, off, 64);
      int  i2 = __shfl_xor(mi, off, 64);
      if (v2 > v || (v2 == v && i2 < mi)){ v = v2; mi = i2; }
    }
    if (it == 0) vmax = v;
    if ((mi & 63) == lane) km |= 1 << (mi >> 6);
  }
  float a = sigf(alp[0]);
  float eneg = __expf(-vmax);
  float p[4]; float ps = 0.f;
  #pragma unroll
  for (int q=0;q<4;++q){
    p[q] = 0.f;
    if (d[q] >= 0.f) p[q] = ((km>>q)&1) ? __expf(d[q]-vmax) : eneg;
    ps += p[q];
  }
  #pragma unroll
  for (int off=1; off<64; off<<=1) ps += __shfl_xor(ps, off, 64);
  float inv = (1.f - a)/ps;
  float rs = 0.f;
  #pragma unroll
  for (int q=0;q<4;++q){
    int m = lane + q*64;
    if (m < NNODE){
      float Av = a*Aph[n*NNODE + m] + p[q]*inv;
      Abuf[(size_t)row*LSTR + m] = Av;
      rs += Av;
    }
  }
  if (lane == 0) Abuf[(size_t)row*LSTR + 207] = 0.f;
  #pragma unroll
  for (int off=1; off<64; off<<=1) rs += __shfl_xor(rs, off, 64);
  if (lane == 0) rsum[row] = rs;
}

__global__ __launch_bounds__(256) void k_lam(const float* __restrict__ rsum, float* __restrict__ lam){
  __shared__ float rv[256];
  int b = blockIdx.x, tid = threadIdx.x;
  rv[tid] = (tid < NNODE) ? rsum[b*NNODE+tid] : -1e30f;
  __syncthreads();
  for (int s=128;s>0;s>>=1){ if (tid<s) rv[tid]=fmaxf(rv[tid],rv[tid+s]); __syncthreads(); }
  if (tid==0) lam[b] = fmaxf(rv[0], 1.0f);
}

__global__ __launch_bounds__(256) void k_lap(float* __restrict__ Abuf, const float* __restrict__ lam){
  int idx = blockIdx.x*256 + threadIdx.x;
  if (idx >= NB*NNODE*LSTR) return;
  int b = idx / (NNODE*LSTR);
  int rem = idx % (NNODE*LSTR);
  int n = rem / LSTR, m = rem % LSTR;
  Abuf[idx] = 2.f*Abuf[idx]/lam[b] - (n==m ? 1.f : 0.f);
}

// causal conv(3) + GLU
__global__ __launch_bounds__(256) void k_tcn(const float* __restrict__ x,
    const float* __restrict__ w, const float* __restrict__ bcn, float* __restrict__ tfeat){
  int idx = blockIdx.x*256 + threadIdx.x;
  if (idx >= BTN*32) return;
  int o = idx & 31; int r = idx >> 5;
  int n = r % NNODE, bt = r / NNODE, t = bt % NT, b = bt / NT;
  float t0 = (t>=2)? x[((size_t)(b*NT+t-2)*NNODE+n)*NF] : 0.f;
  float t1 = (t>=1)? x[((size_t)(b*NT+t-1)*NNODE+n)*NF] : 0.f;
  float t2 = x[((size_t)(b*NT+t)*NNODE+n)*NF];
  float P = bcn[o]    + w[o*3]*t0       + w[o*3+1]*t1       + w[o*3+2]*t2;
  float Q = bcn[o+32] + w[(o+32)*3]*t0  + w[(o+32)*3+1]*t1  + w[(o+32)*3+2]*t2;
  tfeat[(size_t)r*32 + o] = P * sigf(Q);
}

__global__ __launch_bounds__(256) void k_thetaBC(const float* __restrict__ tfeat,
    const float* __restrict__ theta, float* __restrict__ P2, float* __restrict__ P1){
  __shared__ float thB[32][33], thC[32][33];
  __shared__ float tf[8][32];
  int tid = threadIdx.x;
  for (int i=tid; i<1024; i+=256){
    int f = i >> 5, o = i & 31;
    thB[o][f] = theta[1024+f*32+o]; thC[o][f] = theta[2048+f*32+o];
  }
  int rl = tid >> 5, o = tid & 31;
  int r = blockIdx.x*8 + rl;
  tf[rl][o] = tfeat[(size_t)r*32 + o];
  __syncthreads();
  float aB=0.f, aC=0.f;
  #pragma unroll
  for (int f=0; f<32; ++f){
    float t = tf[rl][f];
    aB += t*thB[o][f]; aC += t*thC[o][f];
  }
  int n = r % NNODE, bt = r / NNODE, t = bt % NT, b = bt / NT;
  size_t outi = (size_t)(b*NNODE+n)*G3 + t*32 + o;
  P2[outi]=aB; P1[outi]=aC;
}

__global__ __launch_bounds__(256) void k_thetaA(const float* __restrict__ tfeat,
    const float* __restrict__ theta, float* __restrict__ P1){
  __shared__ float thA[32][33];
  __shared__ float tf[8][32];
  int tid = threadIdx.x;
  for (int i=tid; i<1024; i+=256){
    int f = i >> 5, o = i & 31;
    thA[o][f] = theta[f*32+o] - theta[2048+f*32+o];
  }
  int rl = tid >> 5, o = tid & 31;
  int r = blockIdx.x*8 + rl;
  tf[rl][o] = tfeat[(size_t)r*32 + o];
  __syncthreads();
  float aA=0.f;
  #pragma unroll
  for (int f=0; f<32; ++f) aA += tf[rl][f]*thA[o][f];
  int n = r % NNODE, bt = r / NNODE, t = bt % NT, b = bt / NT;
  P1[(size_t)(b*NNODE+n)*G3 + t*32 + o] = aA;
}

// ===== MFMA batched GEMM (split-bf16 mm3), N fixed 384 =====
// C = bias ? (A@X + bias) : [relu](alpha*(A@X) + beta*Y)
// A fp32 (M x K, row stride lda); X fp32 (K x 384). 64-row tiles, 512 thr.
__global__ __launch_bounds__(512) void gemm_mfma(
    const float* __restrict__ Ab, int lda, long long sA, int M, int Aklim,
    const float* __restrict__ Xb, long long sX, int Xklim,
    const float* __restrict__ bias,
    const float* __restrict__ Yb, long long sY,
    float alphaV, float betaV, int do_relu,
    float* __restrict__ Cb, long long sC, int mtpb, int kchunks){
  __shared__ float As[32*68];     // transposed [k][row]
  __shared__ float Xs[32*388];    // [k][col]
  int bz = blockIdx.x / mtpb;
  int mt = blockIdx.x % mtpb;
  int m0 = mt*64;
  const float* A = Ab + (size_t)bz*sA;
  const float* X = Xb + (size_t)bz*sX;
  int tid = threadIdx.x;
  int w = tid>>6, lane = tid&63;
  int c = lane&15, g = lane>>4;
  accf4 acc[4][3] = {};
  for (int kc=0; kc<kchunks; ++kc){
    int k0 = kc*32;
    __syncthreads();
    {  // stage A (transposed): 512 thr x 1 float4 read, 4 b32 writes
      int r_ = tid>>3, kq = (tid&7)*4;
      int row = m0 + r_;
      float4 v = make_float4(0.f,0.f,0.f,0.f);
      if (row < M && (k0+kq) < Aklim)
        v = *(const float4*)&A[(size_t)row*lda + k0 + kq];
      As[(kq+0)*68 + r_] = v.x; As[(kq+1)*68 + r_] = v.y;
      As[(kq+2)*68 + r_] = v.z; As[(kq+3)*68 + r_] = v.w;
    }
    {  // stage X: 512 thr x 6 float4
      int kr = tid>>4, cb4 = tid&15;
      const float* xr_ = X + (size_t)(k0+kr)*384;
      bool kv = (k0+kr) < Xklim;
      #pragma unroll
      for (int jj=0; jj<6; ++jj){
        int colf = (cb4 + 16*jj)*4;
        float4 v = kv ? *(const float4*)&xr_[colf] : make_float4(0.f,0.f,0.f,0.f);
        *(float4*)&Xs[kr*388 + colf] = v;
      }
    }
    __syncthreads();
    short8 ah[4], al[4];
    #pragma unroll
    for (int rt=0; rt<4; ++rt){
      int row_l = rt*16 + c;
      #pragma unroll
      for (int e=0; e<8; ++e){
        float v = As[(g*8+e)*68 + row_l];
        unsigned short h_ = f2b(v);
        ah[rt][e] = (short)h_;
        al[rt][e] = (short)f2b(v - b2f(h_));
      }
    }
    #pragma unroll
    for (int p=0; p<3; ++p){
      int colg = (w<<4) + (p<<7) + c;
      short8 bh_, bl_;
      #pragma unroll
      for (int e=0; e<8; ++e){
        float v = Xs[(g*8+e)*388 + colg];
        unsigned short h_ = f2b(v);
        bh_[e] = (short)h_;
        bl_[e] = (short)f2b(v - b2f(h_));
      }
      #pragma unroll
      for (int rt=0; rt<4; ++rt) mm3(ah[rt], al[rt], bh_, bl_, acc[rt][p]);
    }
  }
  if (bias){
    #pragma unroll
    for (int p=0; p<3; ++p){
      int colg = (w<<4) + (p<<7) + c;
      float bv = bias[colg];
      #pragma unroll
      for (int rt=0; rt<4; ++rt){
        #pragma unroll
        for (int i=0;i<4;++i){
          int row = m0 + rt*16 + g*4 + i;
          if (row < M)
            Cb[(size_t)bz*sC + (size_t)row*384 + colg] = acc[rt][p][i] + bv;
        }
      }
    }
  } else {
    const float* Y = Yb + (size_t)bz*sY;
    float* C = Cb + (size_t)bz*sC;
    #pragma unroll
    for (int p=0; p<3; ++p){
      int colg = (w<<4) + (p<<7) + c;
      #pragma unroll
      for (int rt=0; rt<4; ++rt){
        #pragma unroll
        for (int i=0;i<4;++i){
          int row = m0 + rt*16 + g*4 + i;
          if (row < M){
            float v = alphaV*acc[rt][p][i] + betaV*Y[(size_t)row*384 + colg];
            if (do_relu) v = fmaxf(v, 0.f);
            C[(size_t)row*384 + colg] = v;
          }
        }
      }
    }
  }
}

// ===================== persistent MFMA encoder+decoder (v3) =====================
#define GATEB(WH, WL, KS) \
    const int ko = (KS)*24; \
    short8 bRh = *(const short8*)(WH + ((size_t)(ko + w)*64 + lane)*8); \
    short8 bZh = *(const short8*)(WH + ((size_t)(ko + 8 + w)*64 + lane)*8); \
    short8 bNh = *(const short8*)(WH + ((size_t)(ko + 16 + w)*64 + lane)*8); \
    short8 bRl = *(const short8*)(WL + ((size_t)(ko + w)*64 + lane)*8); \
    short8 bZl = *(const short8*)(WL + ((size_t)(ko + 8 + w)*64 + lane)*8); \
    short8 bNl = *(const short8*)(WL + ((size_t)(ko + 16 + w)*64 + lane)*8);

__global__ __launch_bounds__(512) void k_encdec(
    const short* __restrict__ zfH, const short* __restrict__ zfL,
    const short* __restrict__ WFH, const short* __restrict__ WFL,
    const float* __restrict__ bih, const float* __restrict__ bhh,
    const short* __restrict__ DFH, const short* __restrict__ DFL,
    const float* __restrict__ dbhh, const float* __restrict__ ctxGX,
    const float* __restrict__ w0, const float* __restrict__ ow,
    const float* __restrict__ ob, const float* __restrict__ pred0,
    float* __restrict__ preds_out){
  __shared__ __attribute__((aligned(16))) short hfH[4*2*512];   // [ks][rt][lane*8+e]
  __shared__ __attribute__((aligned(16))) short hfL[4*2*512];
  __shared__ float psl[8][32];
  __shared__ float predl[32];
  int R = blockIdx.x, m0 = R*32;
  int tid = threadIdx.x;
  int w = tid >> 6, lane = tid & 63;
  int g = lane >> 4, c = lane & 15;
  int j = (w<<4) + c;
  float hreg[2][4] = {};
  for (int i = tid; i < 4096; i += 512){ hfH[i] = 0; hfL[i] = 0; }
  if (tid < 32) predl[tid] = pred0[m0 + tid];
  int ksh = w >> 1, qh = 2*(w&1) + (c>>3), eh = c & 7;
  float birv = bih[j], bizv = bih[128+j], binv = bih[256+j];
  float bhrv = bhh[j], bhzv = bhh[128+j], bhnv = bhh[256+j];
  __syncthreads();

  // -------- encoder: 12 steps --------
  for (int t = 0; t < NT; ++t){
    accf4 aR[2] = {}, aZ[2] = {}, aNZ[2] = {}, aNH[2] = {};
    #pragma unroll
    for (int ks=0; ks<3; ++ks){
      GATEB(WFH, WFL, ks);
      size_t zb = (((size_t)t*RG + R)*3 + ks)*1024;
      #pragma unroll
      for (int rt=0; rt<2; ++rt){
        short8 ah = *(const short8*)(zfH + zb + rt*512 + lane*8);
        short8 al = *(const short8*)(zfL + zb + rt*512 + lane*8);
        mm3(ah, al, bRh, bRl, aR[rt]);
        mm3(ah, al, bZh, bZl, aZ[rt]);
        mm3(ah, al, bNh, bNl, aNZ[rt]);
      }
    }
    #pragma unroll
    for (int ks=3; ks<7; ++ks){
      GATEB(WFH, WFL, ks);
      #pragma unroll
      for (int rt=0; rt<2; ++rt){
        short8 ah = *(const short8*)&hfH[(ks-3)*1024 + rt*512 + lane*8];
        short8 al = *(const short8*)&hfL[(ks-3)*1024 + rt*512 + lane*8];
        mm3(ah, al, bRh, bRl, aR[rt]);
        mm3(ah, al, bZh, bZl, aZ[rt]);
        mm3(ah, al, bNh, bNl, aNH[rt]);
      }
    }
    __syncthreads();   // all hf reads done
    #pragma unroll
    for (int rt=0; rt<2; ++rt){
      #pragma unroll
      for (int i=0;i<4;++i){
        float r_ = sigf(aR[rt][i] + birv + bhrv);
        float z_ = sigf(aZ[rt][i] + bizv + bhzv);
        float n_ = tanhf(aNZ[rt][i] + binv + r_*(aNH[rt][i] + bhnv));
        float hn = (1.f - z_)*n_ + z_*hreg[rt][i];
        hreg[rt][i] = hn;
        unsigned short hh = f2b(hn);
        int o = ksh*1024 + rt*512 + ((g*4+i) + 16*qh)*8 + eh;
        hfH[o] = (short)hh;
        hfL[o] = (short)f2b(hn - b2f(hh));
      }
    }
    __syncthreads();   // hf writes visible
  }

  // -------- decoder: 12 steps --------
  float w0r = w0[j], w0z = w0[128+j], w0n = w0[256+j];
  float bhr = dbhh[j], bhz = dbhh[128+j], bhn = dbhh[256+j];
  float owj = ow[j];
  float obv = ob[0];
  for (int s = 0; s < NT; ++s){
    accf4 aR[2] = {}, aZ[2] = {}, aN[2] = {};
    #pragma unroll
    for (int ks=0; ks<4; ++ks){
      GATEB(DFH, DFL, ks);
      #pragma unroll
      for (int rt=0; rt<2; ++rt){
        short8 ah = *(const short8*)&hfH[ks*1024 + rt*512 + lane*8];
        short8 al = *(const short8*)&hfL[ks*1024 + rt*512 + lane*8];
        mm3(ah, al, bRh, bRl, aR[rt]);
        mm3(ah, al, bZh, bZl, aZ[rt]);
        mm3(ah, al, bNh, bNl, aN[rt]);
      }
    }
    __syncthreads();   // hf reads done; predl from prev step visible
    #pragma unroll
    for (int rt=0; rt<2; ++rt){
      #pragma unroll
      for (int i=0;i<4;++i){
        int row = rt*16 + g*4 + i;
        float p = predl[row];
        const float* gx = ctxGX + (size_t)(m0+row)*384;
        float r_ = sigf(gx[j]     + p*w0r + aR[rt][i] + bhr);
        float z_ = sigf(gx[128+j] + p*w0z + aZ[rt][i] + bhz);
        float n_ = tanhf(gx[256+j] + p*w0n + r_*(aN[rt][i] + bhn));
        float hn = (1.f - z_)*n_ + z_*hreg[rt][i];
        hreg[rt][i] = hn;
        unsigned short hh = f2b(hn);
        int o = ksh*1024 + rt*512 + ((g*4+i) + 16*qh)*8 + eh;
        hfH[o] = (short)hh;
        hfL[o] = (short)f2b(hn - b2f(hh));
        float psv = hn*owj;
        psv += __shfl_xor(psv, 1, 64);
        psv += __shfl_xor(psv, 2, 64);
        psv += __shfl_xor(psv, 4, 64);
        psv += __shfl_xor(psv, 8, 64);
        if (c == 0) psl[w][row] = psv;
      }
    }
    __syncthreads();   // hf + psl writes visible
    if (tid < 32){
      float sm = obv;
      #pragma unroll
      for (int w2=0; w2<8; ++w2) sm += psl[w2][tid];
      predl[tid] = sm;
      preds_out[(size_t)s*ROWS + m0 + tid] = sm;
    }
  }
}

// fusion + attn gate; writes z pre-split into MFMA A-frag layout (zfH/zfL)
__global__ __launch_bounds__(256) void k_zbuild(const float* __restrict__ x,
    const float* __restrict__ S, const float* __restrict__ cw, const float* __restrict__ cb,
    const float* __restrict__ aw, const float* __restrict__ ab,
    short* __restrict__ zfH, short* __restrict__ zfL,
    float* __restrict__ ctx, float* __restrict__ pred0){
  __shared__ float cwl[416];
  __shared__ float cbl[32];
  __shared__ float awl[65];
  int tid = threadIdx.x;
  for (int i=tid; i<416; i+=256) cwl[i] = cw[i];
  if (tid < 32) cbl[tid] = cb[tid];
  if (tid < 65) awl[tid] = aw[tid];
  __syncthreads();
  int wid = tid >> 6, sel = (tid >> 5) & 1, hl = tid & 31;
  int r = blockIdx.x*8 + wid*2 + sel;
  int n = r % NNODE, bt = r / NNODE, t = bt % NT, b = bt / NT;
  const float* xr = x + (size_t)r*NF;
  float x0 = xr[0];
  float s_ = cbl[hl];
  #pragma unroll
  for (int f=0; f<13; ++f) s_ += xr[1+f]*cwl[hl*13+f];
  float ce = s_ > 0.f ? s_ : 0.f;
  float sv = S[(size_t)(b*NNODE+n)*G3 + t*32 + hl];
  float part = sv*awl[1+hl] + ce*awl[33+hl] + (hl==0 ? x0*awl[0] : 0.f);
  part += __shfl_xor(part, 1, 64);
  part += __shfl_xor(part, 2, 64);
  part += __shfl_xor(part, 4, 64);
  part += __shfl_xor(part, 8, 64);
  part += __shfl_xor(part, 16, 64);
  float attn = sigf(part + ab[0]);
  int i_ = r / NT, tau = r % NT;          // scrambled reshape (B*N, T, 65)
  int Rg = i_ >> 5, rt = (i_ >> 4) & 1, rowin = i_ & 15;
  size_t basez = ((size_t)tau*RG + Rg)*3*1024 + rt*512;
  #define ZPUT(L, V) do{ int l_=(L); int ks_=l_>>5, q_=(l_&31)>>3, e_=l_&7; \
      size_t o_ = basez + (size_t)ks_*1024 + ((rowin + 16*q_)<<3) + e_; \
      float v_=(V); unsigned short hh_ = f2b(v_); \
      zfH[o_] = (short)hh_; zfL[o_] = (short)f2b(v_ - b2f(hh_)); }while(0)
  ZPUT(1+hl, sv*attn);
  ZPUT(33+hl, ce*attn);
  if (hl == 0) ZPUT(0, x0*attn);
  if (hl <= 30) ZPUT(65+hl, 0.f);   // pad l=65..95
  #undef ZPUT
  if (t == NT-1){
    ctx[(size_t)(b*NNODE+n)*32 + hl] = ce;
    if (hl == 0) pred0[b*NNODE+n] = x0;
  }
}

__global__ __launch_bounds__(256) void k_out(const float* __restrict__ preds, float* __restrict__ out){
  int idx = blockIdx.x*256 + threadIdx.x;
  if (idx >= NT*ROWS) return;
  int n = idx % NNODE;
  int t2 = idx / NNODE;
  int hor = t2 % NT;
  int b = t2 / NT;
  out[idx] = preds[(size_t)hor*ROWS + b*NNODE + n];
}

extern "C" void kernel_launch(void* const* d_in, const int* in_sizes, int n_in,
                              void* d_out, int out_size, void* d_ws, size_t ws_size,
                              hipStream_t stream){
  const float* x     = (const float*)d_in[0];
  const float* Aph   = (const float*)d_in[1];
  const float* fcw   = (const float*)d_in[2];
  const float* fcb   = (const float*)d_in[3];
  const float* alp   = (const float*)d_in[4];
  const float* cw    = (const float*)d_in[5];
  const float* cb    = (const float*)d_in[6];
  const float* tw    = (const float*)d_in[7];
  const float* tb    = (const float*)d_in[8];
  const float* theta = (const float*)d_in[9];
  const float* aw    = (const float*)d_in[10];
  const float* ab    = (const float*)d_in[11];
  const float* ewih  = (const float*)d_in[12];
  const float* ewhh  = (const float*)d_in[13];
  const float* ebih  = (const float*)d_in[14];
  const float* ebhh  = (const float*)d_in[15];
  const float* dwih  = (const float*)d_in[16];
  const float* dwhh  = (const float*)d_in[17];
  const float* dbih  = (const float*)d_in[18];
  const float* dbhh  = (const float*)d_in[19];
  const float* ow    = (const float*)d_in[20];
  const float* ob    = (const float*)d_in[21];
  float* out = (float*)d_out;

  const size_t SZ_CTX  = (size_t)ROWS*32;
  const size_t SZ_PRED = (size_t)ROWS;
  const size_t SZ_PREDS= (size_t)NT*ROWS;
  const size_t SZ_G    = (size_t)ROWS*G3;
  const size_t SZ_ABUF = (size_t)NB*NNODE*LSTR;
  const size_t SZ_EMB  = (size_t)ROWS*16;
  const size_t SZ_ZF   = (size_t)NT*RG*3*1024;          // shorts per array
  const size_t SZ_UNION_FL = (2*SZ_ZF + 3) / 2;          // zfH+zfL in floats
  const size_t UNION_FL = (SZ_UNION_FL > 2*SZ_G) ? SZ_UNION_FL : 2*SZ_G;

  float* w = (float*)d_ws;
  size_t off = 0;
  auto alloc = [&](size_t nfl){ float* p = w + off; off += nfl; return p; };
  float* ctx   = alloc(SZ_CTX);
  float* pred  = alloc(SZ_PRED);
  float* preds = alloc(SZ_PREDS);
  float* Abuf  = alloc(SZ_ABUF);
  float* emb   = alloc(SZ_EMB);
  float* rsum  = alloc(SZ_PRED);
  float* lam   = alloc((size_t)NB);
  short* wS    = (short*)alloc(SH_TOTAL/2);
  float* wF    = alloc((size_t)FWT_TOTAL);
  float* Sslot = alloc(SZ_G);      // t_feat -> S -> ctxGX
  float* Uzone = alloc(UNION_FL);  // P1 | P2 during Chebyshev; zfH|zfL after
  float* P1 = Uzone;
  float* P2 = Uzone + SZ_G;
  short* zfH = (short*)Uzone;
  short* zfL = zfH + SZ_ZF;
  (void)n_in; (void)in_sizes;

  if (ws_size < off*sizeof(float)){    // tripwire: workspace too small
    k_sentinel<<<(out_size+255)/256, 256, 0, stream>>>(out, out_size);
    return;
  }

  const short* WFH = wS;
  const short* WFL = wS + NW_ENC;
  const short* DFH = wS + 2*NW_ENC;
  const short* DFL = wS + 2*NW_ENC + NW_DEC;
  float* dwihT = wF;
  float* w0    = wF + 32*384;

  k_prep<<<(PREP_TOTAL+255)/256, 256, 0, stream>>>(ewih, ewhh, dwih, dwhh, wS, wF);
  float* tfeat = Sslot;
  k_emb<<<(ROWS*16)/256, 256, 0, stream>>>(x, fcw, fcb, emb);
  k_adj<<<ROWS/4, 256, 0, stream>>>(emb, Aph, alp, Abuf, rsum);
  k_lam<<<NB, 256, 0, stream>>>(rsum, lam);
  k_lap<<<(NB*NNODE*LSTR)/256, 256, 0, stream>>>(Abuf, lam);
  k_tcn<<<(BTN*32)/256, 256, 0, stream>>>(x, tw, tb, tfeat);
  k_thetaBC<<<BTN/8, 256, 0, stream>>>(tfeat, theta, P2, P1);
  // P2 <- 2*(L @ P1) + P2   (MFMA)
  gemm_mfma<<<NB*4, 512, 0, stream>>>(Abuf, LSTR, (long long)NNODE*LSTR, NNODE, 208,
      P1, (long long)NNODE*G3, NNODE, nullptr,
      P2, (long long)NNODE*G3, 2.f, 1.f, 0,
      P2, (long long)NNODE*G3, 4, 7);
  k_thetaA<<<BTN/8, 256, 0, stream>>>(tfeat, theta, P1);
  // Sslot <- relu((L @ P2) + P1)   (MFMA)
  gemm_mfma<<<NB*4, 512, 0, stream>>>(Abuf, LSTR, (long long)NNODE*LSTR, NNODE, 208,
      P2, (long long)NNODE*G3, NNODE, nullptr,
      P1, (long long)NNODE*G3, 1.f, 1.f, 1,
      Sslot, (long long)NNODE*G3, 4, 7);
  k_zbuild<<<BTN/8, 256, 0, stream>>>(x, Sslot, cw, cb, aw, ab, zfH, zfL, ctx, pred);
  float* ctxGX = Sslot;  // S dead after zbuild
  // ctxGX <- ctx @ dwihT + dbih   (MFMA, K=32)
  gemm_mfma<<<ROWS/64, 512, 0, stream>>>(ctx, 32, 0, ROWS, 32,
      dwihT, 0, 32, dbih,
      nullptr, 0, 1.f, 0.f, 0,
      ctxGX, 0, ROWS/64, 1);
  k_encdec<<<RG, 512, 0, stream>>>(zfH, zfL, WFH, WFL, ebih, ebhh,
      DFH, DFL, dbhh, ctxGX, w0, ow, ob, pred, preds);
  k_out<<<(NT*ROWS)/256, 256, 0, stream>>>(preds, out);
}

// Round 12
// 940.609 us; speedup vs baseline: 1.0400x; 1.0400x over previous
//
#include <hip/hip_runtime.h>
#include <math.h>

#define NB 128      // B
#define NT 12       // T
#define NNODE 207   // N
#define NF 14       // F
#define NH 128      // H
#define ROWS (NB*NNODE)      // 26496
#define BTN (NB*NT*NNODE)    // 317952
#define G3 (3*NH)            // 384
#define LSTR 208             // padded Laplacian row stride
#define RG (ROWS/32)         // 828 row-groups of 32

typedef __attribute__((ext_vector_type(8))) short short8;   // 8 bf16 = 4 VGPR
typedef __attribute__((ext_vector_type(4))) float accf4;    // MFMA C/D

#define MFMA16 __builtin_amdgcn_mfma_f32_16x16x32_bf16

__device__ __forceinline__ float sigf(float x){ return 1.0f/(1.0f+__expf(-x)); }
__device__ __forceinline__ unsigned short f2b(float f){
  unsigned int u = __float_as_uint(f);
  return (unsigned short)((u + 0x7FFFu + ((u>>16)&1u)) >> 16);
}
__device__ __forceinline__ float b2f(unsigned short h){
  return __uint_as_float(((unsigned int)h) << 16);
}
// split-bf16 3-term product: hi*hi + lo*hi + hi*lo (lo*lo ~2^-16, negligible)
__device__ __forceinline__ void mm3(short8 ah, short8 al, short8 bh, short8 bl, accf4& acc){
  acc = MFMA16(ah, bh, acc, 0,0,0);
  acc = MFMA16(al, bh, acc, 0,0,0);
  acc = MFMA16(ah, bl, acc, 0,0,0);
}

__global__ __launch_bounds__(256) void k_sentinel(float* __restrict__ out, int n){
  int i = blockIdx.x*256 + threadIdx.x;
  if (i < n) out[i] = 12345.0f;
}

// ---- weight prep (fragment-layout bf16 hi/lo) ----
#define NW_ENC (7*24*64*8)   // 86016
#define NW_DEC (4*24*64*8)   // 49152
#define SH_TOTAL (2*NW_ENC + 2*NW_DEC)
#define FWT_TOTAL (32*384 + 384)
#define PREP_TOTAL (NW_ENC + NW_DEC + 32*384 + 384)
__global__ __launch_bounds__(256) void k_prep(const float* __restrict__ ewih,
    const float* __restrict__ ewhh, const float* __restrict__ dwih,
    const float* __restrict__ dwhh, short* __restrict__ ws, float* __restrict__ wf){
  int i = blockIdx.x*256 + threadIdx.x;
  if (i < NW_ENC){
    int e = i & 7, lane = (i>>3) & 63, ct = (i>>9) % 24, ks = i / 12288;
    int k = ks*32 + (lane>>4)*8 + e;
    int col = ct*16 + (lane&15);
    float wv = (k < 65) ? ewih[col*65 + k] : ((k < 96) ? 0.f : ewhh[col*128 + (k-96)]);
    unsigned short hi = f2b(wv);
    ws[i] = (short)hi;
    ws[NW_ENC + i] = (short)f2b(wv - b2f(hi));
  } else if (i < NW_ENC + NW_DEC){
    int j = i - NW_ENC;
    int e = j & 7, lane = (j>>3) & 63, ct = (j>>9) % 24, ks = j / 12288;
    int k = ks*32 + (lane>>4)*8 + e;
    int col = ct*16 + (lane&15);
    float wv = dwhh[col*128 + k];
    unsigned short hi = f2b(wv);
    ws[2*NW_ENC + j] = (short)hi;
    ws[2*NW_ENC + NW_DEC + j] = (short)f2b(wv - b2f(hi));
  } else if (i < NW_ENC + NW_DEC + 32*384){
    int j = i - (NW_ENC + NW_DEC); int k = j/384, n = j%384;
    wf[j] = dwih[n*33 + 1 + k];
  } else if (i < PREP_TOTAL){
    int n = i - (NW_ENC + NW_DEC + 32*384);
    wf[32*384 + n] = dwih[n*33];
  }
}

// emb = tanh(state * fc_w + fc_b)
__global__ __launch_bounds__(256) void k_emb(const float* __restrict__ x,
    const float* __restrict__ w, const float* __restrict__ b, float* __restrict__ emb){
  int idx = blockIdx.x*256 + threadIdx.x;
  if (idx >= ROWS*16) return;
  int j = idx & 15, row = idx >> 4;
  int bb = row / NNODE, n = row % NNODE;
  float s = x[((bb*NT + (NT-1))*NNODE + n)*NF];
  emb[idx] = tanhf(s*w[j] + b[j]);
}

// wave-per-row adjacency
__global__ __launch_bounds__(256) void k_adj(const float* __restrict__ emb,
    const float* __restrict__ Aph, const float* __restrict__ alp,
    float* __restrict__ Abuf, float* __restrict__ rsum){
  int wid = threadIdx.x >> 6, lane = threadIdx.x & 63;
  int row = blockIdx.x*4 + wid;
  int bb = row / NNODE, n = row % NNODE;
  const float4* er = (const float4*)(emb + (size_t)row*16);
  float4 e0 = er[0], e1 = er[1], e2 = er[2], e3 = er[3];
  float d[4];
  #pragma unroll
  for (int q=0;q<4;++q){
    int m = lane + q*64;
    float dd = -1.f;
    if (m < NNODE){
      const float4* em = (const float4*)(emb + (size_t)(bb*NNODE+m)*16);
      float4 m0 = em[0], m1 = em[1], m2 = em[2], m3 = em[3];
      dd = e0.x*m0.x + e0.y*m0.y + e0.z*m0.z + e0.w*m0.w
         + e1.x*m1.x + e1.y*m1.y + e1.z*m1.z + e1.w*m1.w
         + e2.x*m2.x + e2.y*m2.y + e2.z*m2.z + e2.w*m2.w
         + e3.x*m3.x + e3.y*m3.y + e3.z*m3.z + e3.w*m3.w;
      dd = dd > 0.f ? dd : 0.f;
    }
    d[q] = dd;
  }
  int km = 0;
  float vmax = 0.f;
  for (int it=0; it<10; ++it){
    float v = -1.f; int mi = 1<<20;
    #pragma unroll
    for (int q=0;q<4;++q){
      if (d[q] >= 0.f && !((km>>q)&1) && d[q] > v){ v = d[q]; mi = lane + q*64; }
    }
    #pragma unroll
    for (int off=1; off<64; off<<=1){
      float v2 = __shfl_xor(v, off, 64);
      int  i2 = __shfl_xor(mi, off, 64);
      if (v2 > v || (v2 == v && i2 < mi)){ v = v2; mi = i2; }
    }
    if (it == 0) vmax = v;
    if ((mi & 63) == lane) km |= 1 << (mi >> 6);
  }
  float a = sigf(alp[0]);
  float eneg = __expf(-vmax);
  float p[4]; float ps = 0.f;
  #pragma unroll
  for (int q=0;q<4;++q){
    p[q] = 0.f;
    if (d[q] >= 0.f) p[q] = ((km>>q)&1) ? __expf(d[q]-vmax) : eneg;
    ps += p[q];
  }
  #pragma unroll
  for (int off=1; off<64; off<<=1) ps += __shfl_xor(ps, off, 64);
  float inv = (1.f - a)/ps;
  float rs = 0.f;
  #pragma unroll
  for (int q=0;q<4;++q){
    int m = lane + q*64;
    if (m < NNODE){
      float Av = a*Aph[n*NNODE + m] + p[q]*inv;
      Abuf[(size_t)row*LSTR + m] = Av;
      rs += Av;
    }
  }
  if (lane == 0) Abuf[(size_t)row*LSTR + 207] = 0.f;
  #pragma unroll
  for (int off=1; off<64; off<<=1) rs += __shfl_xor(rs, off, 64);
  if (lane == 0) rsum[row] = rs;
}

__global__ __launch_bounds__(256) void k_lam(const float* __restrict__ rsum, float* __restrict__ lam){
  __shared__ float rv[256];
  int b = blockIdx.x, tid = threadIdx.x;
  rv[tid] = (tid < NNODE) ? rsum[b*NNODE+tid] : -1e30f;
  __syncthreads();
  for (int s=128;s>0;s>>=1){ if (tid<s) rv[tid]=fmaxf(rv[tid],rv[tid+s]); __syncthreads(); }
  if (tid==0) lam[b] = fmaxf(rv[0], 1.0f);
}

__global__ __launch_bounds__(256) void k_lap(float* __restrict__ Abuf, const float* __restrict__ lam){
  int idx = blockIdx.x*256 + threadIdx.x;
  if (idx >= NB*NNODE*LSTR) return;
  int b = idx / (NNODE*LSTR);
  int rem = idx % (NNODE*LSTR);
  int n = rem / LSTR, m = rem % LSTR;
  Abuf[idx] = 2.f*Abuf[idx]/lam[b] - (n==m ? 1.f : 0.f);
}

// causal conv(3) + GLU
__global__ __launch_bounds__(256) void k_tcn(const float* __restrict__ x,
    const float* __restrict__ w, const float* __restrict__ bcn, float* __restrict__ tfeat){
  int idx = blockIdx.x*256 + threadIdx.x;
  if (idx >= BTN*32) return;
  int o = idx & 31; int r = idx >> 5;
  int n = r % NNODE, bt = r / NNODE, t = bt % NT, b = bt / NT;
  float t0 = (t>=2)? x[((size_t)(b*NT+t-2)*NNODE+n)*NF] : 0.f;
  float t1 = (t>=1)? x[((size_t)(b*NT+t-1)*NNODE+n)*NF] : 0.f;
  float t2 = x[((size_t)(b*NT+t)*NNODE+n)*NF];
  float P = bcn[o]    + w[o*3]*t0       + w[o*3+1]*t1       + w[o*3+2]*t2;
  float Q = bcn[o+32] + w[(o+32)*3]*t0  + w[(o+32)*3+1]*t1  + w[(o+32)*3+2]*t2;
  tfeat[(size_t)r*32 + o] = P * sigf(Q);
}

__global__ __launch_bounds__(256) void k_thetaBC(const float* __restrict__ tfeat,
    const float* __restrict__ theta, float* __restrict__ P2, float* __restrict__ P1){
  __shared__ float thB[32][33], thC[32][33];
  __shared__ float tf[8][32];
  int tid = threadIdx.x;
  for (int i=tid; i<1024; i+=256){
    int f = i >> 5, o = i & 31;
    thB[o][f] = theta[1024+f*32+o]; thC[o][f] = theta[2048+f*32+o];
  }
  int rl = tid >> 5, o = tid & 31;
  int r = blockIdx.x*8 + rl;
  tf[rl][o] = tfeat[(size_t)r*32 + o];
  __syncthreads();
  float aB=0.f, aC=0.f;
  #pragma unroll
  for (int f=0; f<32; ++f){
    float t = tf[rl][f];
    aB += t*thB[o][f]; aC += t*thC[o][f];
  }
  int n = r % NNODE, bt = r / NNODE, t = bt % NT, b = bt / NT;
  size_t outi = (size_t)(b*NNODE+n)*G3 + t*32 + o;
  P2[outi]=aB; P1[outi]=aC;
}

__global__ __launch_bounds__(256) void k_thetaA(const float* __restrict__ tfeat,
    const float* __restrict__ theta, float* __restrict__ P1){
  __shared__ float thA[32][33];
  __shared__ float tf[8][32];
  int tid = threadIdx.x;
  for (int i=tid; i<1024; i+=256){
    int f = i >> 5, o = i & 31;
    thA[o][f] = theta[f*32+o] - theta[2048+f*32+o];
  }
  int rl = tid >> 5, o = tid & 31;
  int r = blockIdx.x*8 + rl;
  tf[rl][o] = tfeat[(size_t)r*32 + o];
  __syncthreads();
  float aA=0.f;
  #pragma unroll
  for (int f=0; f<32; ++f) aA += tf[rl][f]*thA[o][f];
  int n = r % NNODE, bt = r / NNODE, t = bt % NT, b = bt / NT;
  P1[(size_t)(b*NNODE+n)*G3 + t*32 + o] = aA;
}

// ---- fp32 128x128 GEMM (Chebyshev + ctxGX) ----
__global__ __launch_bounds__(256) void gemm128(
    const float* __restrict__ Ab, int lda, long long sA,
    const float* __restrict__ Bb, long long sB,
    const float* __restrict__ bias,
    const float* __restrict__ Yb, long long sY, float alphaV, float betaV, int do_relu,
    float* __restrict__ Cb, long long sC, int M, int kchunks){
  __shared__ float As[16][132];
  __shared__ float Bs[16][132];
  int bz = blockIdx.z;
  const float* A = Ab + (size_t)bz*sA;
  const float* B = Bb + (size_t)bz*sB;
  float* C = Cb + (size_t)bz*sC;
  int n0 = blockIdx.x*128, m0 = blockIdx.y*128;
  int tid = threadIdx.x, tx = tid & 15, ty = tid >> 4;
  float acc[8][8] = {};
  int ar = tid & 127, ak = (tid >> 7)*8;
  int bk = tid >> 4, bn = (tid & 15)*8;
  for (int kc=0; kc<kchunks; ++kc){
    int k0 = kc*16;
    int m = m0 + ar;
    if (m < M){
      const float* ap = A + (size_t)m*lda + k0 + ak;
      float4 v0 = *(const float4*)ap, v1 = *(const float4*)(ap+4);
      As[ak+0][ar]=v0.x; As[ak+1][ar]=v0.y; As[ak+2][ar]=v0.z; As[ak+3][ar]=v0.w;
      As[ak+4][ar]=v1.x; As[ak+5][ar]=v1.y; As[ak+6][ar]=v1.z; As[ak+7][ar]=v1.w;
    } else {
      #pragma unroll
      for (int j=0;j<8;++j) As[ak+j][ar]=0.f;
    }
    const float* bp = B + (size_t)(k0+bk)*384 + n0 + bn;
    float4 w0_ = *(const float4*)bp, w1_ = *(const float4*)(bp+4);
    *(float4*)&Bs[bk][bn] = w0_; *(float4*)&Bs[bk][bn+4] = w1_;
    __syncthreads();
    #pragma unroll
    for (int kk=0;kk<16;++kk){
      float4 a0 = *(const float4*)&As[kk][ty*8];
      float4 a1 = *(const float4*)&As[kk][ty*8+4];
      float4 b0 = *(const float4*)&Bs[kk][tx*4];
      float4 b1 = *(const float4*)&Bs[kk][64+tx*4];
      float av[8] = {a0.x,a0.y,a0.z,a0.w,a1.x,a1.y,a1.z,a1.w};
      float bv[8] = {b0.x,b0.y,b0.z,b0.w,b1.x,b1.y,b1.z,b1.w};
      #pragma unroll
      for (int i=0;i<8;++i)
        #pragma unroll
        for (int j=0;j<8;++j) acc[i][j] += av[i]*bv[j];
    }
    __syncthreads();
  }
  if (bias){
    float bl[4], bh_[4];
    #pragma unroll
    for (int j=0;j<4;++j){ bl[j]=bias[n0+tx*4+j]; bh_[j]=bias[n0+64+tx*4+j]; }
    #pragma unroll
    for (int i=0;i<8;++i){
      int m2 = m0 + ty*8 + i; if (m2 >= M) continue;
      float4 s0, s1;
      s0.x=acc[i][0]+bl[0]; s0.y=acc[i][1]+bl[1]; s0.z=acc[i][2]+bl[2]; s0.w=acc[i][3]+bl[3];
      s1.x=acc[i][4]+bh_[0]; s1.y=acc[i][5]+bh_[1]; s1.z=acc[i][6]+bh_[2]; s1.w=acc[i][7]+bh_[3];
      *(float4*)&C[(size_t)m2*384 + n0 + tx*4] = s0;
      *(float4*)&C[(size_t)m2*384 + n0 + 64 + tx*4] = s1;
    }
  } else {
    const float* Y = Yb + (size_t)bz*sY;
    #pragma unroll
    for (int i=0;i<8;++i){
      int m2 = m0 + ty*8 + i; if (m2 >= M) continue;
      const float* yr = Y + (size_t)m2*384;
      float* cr = C + (size_t)m2*384;
      float4 y0 = *(const float4*)(yr + n0 + tx*4);
      float4 y1 = *(const float4*)(yr + n0 + 64 + tx*4);
      float4 s0, s1;
      s0.x = alphaV*acc[i][0] + betaV*y0.x; s0.y = alphaV*acc[i][1] + betaV*y0.y;
      s0.z = alphaV*acc[i][2] + betaV*y0.z; s0.w = alphaV*acc[i][3] + betaV*y0.w;
      s1.x = alphaV*acc[i][4] + betaV*y1.x; s1.y = alphaV*acc[i][5] + betaV*y1.y;
      s1.z = alphaV*acc[i][6] + betaV*y1.z; s1.w = alphaV*acc[i][7] + betaV*y1.w;
      if (do_relu){
        s0.x=fmaxf(s0.x,0.f); s0.y=fmaxf(s0.y,0.f); s0.z=fmaxf(s0.z,0.f); s0.w=fmaxf(s0.w,0.f);
        s1.x=fmaxf(s1.x,0.f); s1.y=fmaxf(s1.y,0.f); s1.z=fmaxf(s1.z,0.f); s1.w=fmaxf(s1.w,0.f);
      }
      *(float4*)(cr + n0 + tx*4) = s0;
      *(float4*)(cr + n0 + 64 + tx*4) = s1;
    }
  }
}

// ===================== persistent MFMA encoder+decoder (v4) =====================
// 32 rows/block (grid 828), 512 threads (8 waves), __launch_bounds__(512,2):
// register double-buffered weights, z prefetched one step ahead, decoder
// weights fully hoisted. 2 barriers per step.
#define LOADW_E(Hb, Lb, KS) do{ \
    size_t kb = (size_t)((KS)*24 + w)*512 + (size_t)lane*8; \
    Hb[0] = *(const short8*)(WFH + kb); \
    Hb[1] = *(const short8*)(WFH + kb + 4096); \
    Hb[2] = *(const short8*)(WFH + kb + 8192); \
    Lb[0] = *(const short8*)(WFL + kb); \
    Lb[1] = *(const short8*)(WFL + kb + 4096); \
    Lb[2] = *(const short8*)(WFL + kb + 8192); \
  }while(0)

#define MM_Z(KS, Wh, Wl) do{ \
    _Pragma("unroll") \
    for (int rt=0; rt<2; ++rt){ \
      mm3(zh[KS][rt], zl[KS][rt], Wh[0], Wl[0], aR[rt]); \
      mm3(zh[KS][rt], zl[KS][rt], Wh[1], Wl[1], aZ[rt]); \
      mm3(zh[KS][rt], zl[KS][rt], Wh[2], Wl[2], aNZ[rt]); \
    } }while(0)

#define MM_H(KH, Wh, Wl, AN) do{ \
    _Pragma("unroll") \
    for (int rt=0; rt<2; ++rt){ \
      short8 ah = *(const short8*)&hfH[(KH)*1024 + rt*512 + lane*8]; \
      short8 al = *(const short8*)&hfL[(KH)*1024 + rt*512 + lane*8]; \
      mm3(ah, al, Wh[0], Wl[0], aR[rt]); \
      mm3(ah, al, Wh[1], Wl[1], aZ[rt]); \
      mm3(ah, al, Wh[2], Wl[2], AN[rt]); \
    } }while(0)

#define LOADZ(T) do{ \
    size_t zb0 = ((size_t)(T)*RG + R)*3072; \
    _Pragma("unroll") \
    for (int ks_=0; ks_<3; ++ks_) \
      _Pragma("unroll") \
      for (int rt=0; rt<2; ++rt){ \
        zh[ks_][rt] = *(const short8*)(zfH + zb0 + ks_*1024 + rt*512 + lane*8); \
        zl[ks_][rt] = *(const short8*)(zfL + zb0 + ks_*1024 + rt*512 + lane*8); \
      } }while(0)

#define ENC_STEP(T, WA_H, WA_L, WB_H, WB_L) do{ \
    accf4 aR[2]={}, aZ[2]={}, aNZ[2]={}, aNH[2]={}; \
    LOADW_E(WB_H, WB_L, 1);  MM_Z(0, WA_H, WA_L); \
    LOADW_E(WA_H, WA_L, 2);  MM_Z(1, WB_H, WB_L); \
    LOADW_E(WB_H, WB_L, 3);  MM_Z(2, WA_H, WA_L); \
    if ((T)+1 < NT) LOADZ((T)+1); \
    LOADW_E(WA_H, WA_L, 4);  MM_H(0, WB_H, WB_L, aNH); \
    LOADW_E(WB_H, WB_L, 5);  MM_H(1, WA_H, WA_L, aNH); \
    LOADW_E(WA_H, WA_L, 6);  MM_H(2, WB_H, WB_L, aNH); \
    LOADW_E(WB_H, WB_L, 0);  MM_H(3, WA_H, WA_L, aNH); \
    __syncthreads(); \
    _Pragma("unroll") \
    for (int rt=0; rt<2; ++rt){ \
      _Pragma("unroll") \
      for (int i=0;i<4;++i){ \
        float r_ = sigf(aR[rt][i] + birv + bhrv); \
        float z_ = sigf(aZ[rt][i] + bizv + bhzv); \
        float n_ = tanhf(aNZ[rt][i] + binv + r_*(aNH[rt][i] + bhnv)); \
        float hn = (1.f - z_)*n_ + z_*hreg[rt][i]; \
        hreg[rt][i] = hn; \
        unsigned short hh = f2b(hn); \
        int o = ksh*1024 + rt*512 + ((g*4+i) + 16*qh)*8 + eh; \
        hfH[o] = (short)hh; \
        hfL[o] = (short)f2b(hn - b2f(hh)); \
      } \
    } \
    __syncthreads(); \
  }while(0)

__global__ __launch_bounds__(512, 2) void k_encdec(
    const short* __restrict__ zfH, const short* __restrict__ zfL,
    const short* __restrict__ WFH, const short* __restrict__ WFL,
    const float* __restrict__ bih, const float* __restrict__ bhh,
    const short* __restrict__ DFH, const short* __restrict__ DFL,
    const float* __restrict__ dbhh, const float* __restrict__ ctxGX,
    const float* __restrict__ w0, const float* __restrict__ ow,
    const float* __restrict__ ob, const float* __restrict__ pred0,
    float* __restrict__ preds_out){
  __shared__ __attribute__((aligned(16))) short hfH[4*2*512];   // [ks][rt][lane*8+e]
  __shared__ __attribute__((aligned(16))) short hfL[4*2*512];
  __shared__ float psl[8][32];
  __shared__ float predl[32];
  int R = blockIdx.x, m0 = R*32;
  int tid = threadIdx.x;
  int w = tid >> 6, lane = tid & 63;
  int g = lane >> 4, c = lane & 15;
  int j = (w<<4) + c;
  float hreg[2][4] = {};
  for (int i = tid; i < 4096; i += 512){ hfH[i] = 0; hfL[i] = 0; }
  if (tid < 32) predl[tid] = pred0[m0 + tid];
  int ksh = w >> 1, qh = 2*(w&1) + (c>>3), eh = c & 7;
  float birv = bih[j], bizv = bih[128+j], binv = bih[256+j];
  float bhrv = bhh[j], bhzv = bhh[128+j], bhnv = bhh[256+j];

  short8 zh[3][2], zl[3][2];
  short8 wAh[3], wAl[3], wBh[3], wBl[3];
  LOADZ(0);
  LOADW_E(wAh, wAl, 0);
  __syncthreads();

  // -------- encoder: 12 steps (2-step unrolled for buffer parity) --------
  #pragma unroll 1
  for (int t = 0; t < NT; t += 2){
    ENC_STEP(t,   wAh, wAl, wBh, wBl);
    ENC_STEP(t+1, wBh, wBl, wAh, wAl);
  }

  // -------- decoder: hoist all 4 ksteps of weights into registers --------
  short8 dH[4][3], dL[4][3];
  #pragma unroll
  for (int ks=0; ks<4; ++ks){
    size_t kb = (size_t)(ks*24 + w)*512 + (size_t)lane*8;
    dH[ks][0] = *(const short8*)(DFH + kb);
    dH[ks][1] = *(const short8*)(DFH + kb + 4096);
    dH[ks][2] = *(const short8*)(DFH + kb + 8192);
    dL[ks][0] = *(const short8*)(DFL + kb);
    dL[ks][1] = *(const short8*)(DFL + kb + 4096);
    dL[ks][2] = *(const short8*)(DFL + kb + 8192);
  }
  float w0r = w0[j], w0z = w0[128+j], w0n = w0[256+j];
  float bhr = dbhh[j], bhz = dbhh[128+j], bhn = dbhh[256+j];
  float owj = ow[j];
  float obv = ob[0];
  for (int s = 0; s < NT; ++s){
    accf4 aR[2] = {}, aZ[2] = {}, aN[2] = {};
    #pragma unroll
    for (int ks=0; ks<4; ++ks){
      #pragma unroll
      for (int rt=0; rt<2; ++rt){
        short8 ah = *(const short8*)&hfH[ks*1024 + rt*512 + lane*8];
        short8 al = *(const short8*)&hfL[ks*1024 + rt*512 + lane*8];
        mm3(ah, al, dH[ks][0], dL[ks][0], aR[rt]);
        mm3(ah, al, dH[ks][1], dL[ks][1], aZ[rt]);
        mm3(ah, al, dH[ks][2], dL[ks][2], aN[rt]);
      }
    }
    __syncthreads();   // hf reads done; predl from prev step visible
    #pragma unroll
    for (int rt=0; rt<2; ++rt){
      #pragma unroll
      for (int i=0;i<4;++i){
        int row = rt*16 + g*4 + i;
        float p = predl[row];
        const float* gx = ctxGX + (size_t)(m0+row)*384;
        float r_ = sigf(gx[j]     + p*w0r + aR[rt][i] + bhr);
        float z_ = sigf(gx[128+j] + p*w0z + aZ[rt][i] + bhz);
        float n_ = tanhf(gx[256+j] + p*w0n + r_*(aN[rt][i] + bhn));
        float hn = (1.f - z_)*n_ + z_*hreg[rt][i];
        hreg[rt][i] = hn;
        unsigned short hh = f2b(hn);
        int o = ksh*1024 + rt*512 + ((g*4+i) + 16*qh)*8 + eh;
        hfH[o] = (short)hh;
        hfL[o] = (short)f2b(hn - b2f(hh));
        float psv = hn*owj;
        psv += __shfl_xor(psv, 1, 64);
        psv += __shfl_xor(psv, 2, 64);
        psv += __shfl_xor(psv, 4, 64);
        psv += __shfl_xor(psv, 8, 64);
        if (c == 0) psl[w][row] = psv;
      }
    }
    __syncthreads();   // hf + psl writes visible
    if (tid < 32){
      float sm = obv;
      #pragma unroll
      for (int w2=0; w2<8; ++w2) sm += psl[w2][tid];
      predl[tid] = sm;
      preds_out[(size_t)s*ROWS + m0 + tid] = sm;
    }
  }
}

// fusion + attn gate; writes z pre-split into MFMA A-frag layout (zfH/zfL)
__global__ __launch_bounds__(256) void k_zbuild(const float* __restrict__ x,
    const float* __restrict__ S, const float* __restrict__ cw, const float* __restrict__ cb,
    const float* __restrict__ aw, const float* __restrict__ ab,
    short* __restrict__ zfH, short* __restrict__ zfL,
    float* __restrict__ ctx, float* __restrict__ pred0){
  __shared__ float cwl[416];
  __shared__ float cbl[32];
  __shared__ float awl[65];
  int tid = threadIdx.x;
  for (int i=tid; i<416; i+=256) cwl[i] = cw[i];
  if (tid < 32) cbl[tid] = cb[tid];
  if (tid < 65) awl[tid] = aw[tid];
  __syncthreads();
  int wid = tid >> 6, sel = (tid >> 5) & 1, hl = tid & 31;
  int r = blockIdx.x*8 + wid*2 + sel;
  int n = r % NNODE, bt = r / NNODE, t = bt % NT, b = bt / NT;
  const float* xr = x + (size_t)r*NF;
  float x0 = xr[0];
  float s_ = cbl[hl];
  #pragma unroll
  for (int f=0; f<13; ++f) s_ += xr[1+f]*cwl[hl*13+f];
  float ce = s_ > 0.f ? s_ : 0.f;
  float sv = S[(size_t)(b*NNODE+n)*G3 + t*32 + hl];
  float part = sv*awl[1+hl] + ce*awl[33+hl] + (hl==0 ? x0*awl[0] : 0.f);
  part += __shfl_xor(part, 1, 64);
  part += __shfl_xor(part, 2, 64);
  part += __shfl_xor(part, 4, 64);
  part += __shfl_xor(part, 8, 64);
  part += __shfl_xor(part, 16, 64);
  float attn = sigf(part + ab[0]);
  int i_ = r / NT, tau = r % NT;          // scrambled reshape (B*N, T, 65)
  int Rg = i_ >> 5, rt = (i_ >> 4) & 1, rowin = i_ & 15;
  size_t basez = ((size_t)tau*RG + Rg)*3*1024 + rt*512;
  #define ZPUT(L, V) do{ int l_=(L); int ks_=l_>>5, q_=(l_&31)>>3, e_=l_&7; \
      size_t o_ = basez + (size_t)ks_*1024 + ((rowin + 16*q_)<<3) + e_; \
      float v_=(V); unsigned short hh_ = f2b(v_); \
      zfH[o_] = (short)hh_; zfL[o_] = (short)f2b(v_ - b2f(hh_)); }while(0)
  ZPUT(1+hl, sv*attn);
  ZPUT(33+hl, ce*attn);
  if (hl == 0) ZPUT(0, x0*attn);
  if (hl <= 30) ZPUT(65+hl, 0.f);   // pad l=65..95
  #undef ZPUT
  if (t == NT-1){
    ctx[(size_t)(b*NNODE+n)*32 + hl] = ce;
    if (hl == 0) pred0[b*NNODE+n] = x0;
  }
}

__global__ __launch_bounds__(256) void k_out(const float* __restrict__ preds, float* __restrict__ out){
  int idx = blockIdx.x*256 + threadIdx.x;
  if (idx >= NT*ROWS) return;
  int n = idx % NNODE;
  int t2 = idx / NNODE;
  int hor = t2 % NT;
  int b = t2 / NT;
  out[idx] = preds[(size_t)hor*ROWS + b*NNODE + n];
}

extern "C" void kernel_launch(void* const* d_in, const int* in_sizes, int n_in,
                              void* d_out, int out_size, void* d_ws, size_t ws_size,
                              hipStream_t stream){
  const float* x     = (const float*)d_in[0];
  const float* Aph   = (const float*)d_in[1];
  const float* fcw   = (const float*)d_in[2];
  const float* fcb   = (const float*)d_in[3];
  const float* alp   = (const float*)d_in[4];
  const float* cw    = (const float*)d_in[5];
  const float* cb    = (const float*)d_in[6];
  const float* tw    = (const float*)d_in[7];
  const float* tb    = (const float*)d_in[8];
  const float* theta = (const float*)d_in[9];
  const float* aw    = (const float*)d_in[10];
  const float* ab    = (const float*)d_in[11];
  const float* ewih  = (const float*)d_in[12];
  const float* ewhh  = (const float*)d_in[13];
  const float* ebih  = (const float*)d_in[14];
  const float* ebhh  = (const float*)d_in[15];
  const float* dwih  = (const float*)d_in[16];
  const float* dwhh  = (const float*)d_in[17];
  const float* dbih  = (const float*)d_in[18];
  const float* dbhh  = (const float*)d_in[19];
  const float* ow    = (const float*)d_in[20];
  const float* ob    = (const float*)d_in[21];
  float* out = (float*)d_out;

  const size_t SZ_CTX  = (size_t)ROWS*32;
  const size_t SZ_PRED = (size_t)ROWS;
  const size_t SZ_PREDS= (size_t)NT*ROWS;
  const size_t SZ_G    = (size_t)ROWS*G3;
  const size_t SZ_ABUF = (size_t)NB*NNODE*LSTR;
  const size_t SZ_EMB  = (size_t)ROWS*16;
  const size_t SZ_ZF   = (size_t)NT*RG*3*1024;          // shorts per array
  const size_t SZ_UNION_FL = (2*SZ_ZF + 3) / 2;          // zfH+zfL in floats
  const size_t UNION_FL = (SZ_UNION_FL > 2*SZ_G) ? SZ_UNION_FL : 2*SZ_G;

  float* w = (float*)d_ws;
  size_t off = 0;
  auto alloc = [&](size_t nfl){ float* p = w + off; off += nfl; return p; };
  float* ctx   = alloc(SZ_CTX);
  float* pred  = alloc(SZ_PRED);
  float* preds = alloc(SZ_PREDS);
  float* Abuf  = alloc(SZ_ABUF);
  float* emb   = alloc(SZ_EMB);
  float* rsum  = alloc(SZ_PRED);
  float* lam   = alloc((size_t)NB);
  short* wS    = (short*)alloc(SH_TOTAL/2);
  float* wF    = alloc((size_t)FWT_TOTAL);
  float* Sslot = alloc(SZ_G);      // t_feat -> S -> ctxGX
  float* Uzone = alloc(UNION_FL);  // P1 | P2 during Chebyshev; zfH|zfL after
  float* P1 = Uzone;
  float* P2 = Uzone + SZ_G;
  short* zfH = (short*)Uzone;
  short* zfL = zfH + SZ_ZF;
  (void)n_in; (void)in_sizes;

  if (ws_size < off*sizeof(float)){    // tripwire: workspace too small
    k_sentinel<<<(out_size+255)/256, 256, 0, stream>>>(out, out_size);
    return;
  }

  const short* WFH = wS;
  const short* WFL = wS + NW_ENC;
  const short* DFH = wS + 2*NW_ENC;
  const short* DFL = wS + 2*NW_ENC + NW_DEC;
  float* dwihT = wF;
  float* w0    = wF + 32*384;

  k_prep<<<(PREP_TOTAL+255)/256, 256, 0, stream>>>(ewih, ewhh, dwih, dwhh, wS, wF);
  float* tfeat = Sslot;
  k_emb<<<(ROWS*16)/256, 256, 0, stream>>>(x, fcw, fcb, emb);
  k_adj<<<ROWS/4, 256, 0, stream>>>(emb, Aph, alp, Abuf, rsum);
  k_lam<<<NB, 256, 0, stream>>>(rsum, lam);
  k_lap<<<(NB*NNODE*LSTR)/256, 256, 0, stream>>>(Abuf, lam);
  k_tcn<<<(BTN*32)/256, 256, 0, stream>>>(x, tw, tb, tfeat);
  k_thetaBC<<<BTN/8, 256, 0, stream>>>(tfeat, theta, P2, P1);
  // P2 <- 2*(L @ P1) + P2
  gemm128<<<dim3(3, 2, NB), 256, 0, stream>>>(Abuf, LSTR, (long long)NNODE*LSTR,
      P1, (long long)NNODE*G3, nullptr,
      P2, (long long)NNODE*G3, 2.f, 1.f, 0,
      P2, (long long)NNODE*G3, NNODE, 13);
  k_thetaA<<<BTN/8, 256, 0, stream>>>(tfeat, theta, P1);
  // Sslot <- relu((L @ P2) + P1)
  gemm128<<<dim3(3, 2, NB), 256, 0, stream>>>(Abuf, LSTR, (long long)NNODE*LSTR,
      P2, (long long)NNODE*G3, nullptr,
      P1, (long long)NNODE*G3, 1.f, 1.f, 1,
      Sslot, (long long)NNODE*G3, NNODE, 13);
  k_zbuild<<<BTN/8, 256, 0, stream>>>(x, Sslot, cw, cb, aw, ab, zfH, zfL, ctx, pred);
  float* ctxGX = Sslot;  // S dead after zbuild
  gemm128<<<dim3(3, ROWS/128, 1), 256, 0, stream>>>(
      ctx, 32, 0, dwihT, 0, dbih,
      nullptr, 0, 1.f, 0.f, 0, ctxGX, 0, ROWS, 2);
  k_encdec<<<RG, 512, 0, stream>>>(zfH, zfL, WFH, WFL, ebih, ebhh,
      DFH, DFL, dbhh, ctxGX, w0, ow, ob, pred, preds);
  k_out<<<(NT*ROWS)/256, 256, 0, stream>>>(preds, out);
}

// Round 13
// 844.736 us; speedup vs baseline: 1.1580x; 1.1135x over previous
//
#include <hip/hip_runtime.h>
#include <math.h>

#define NB 128      // B
#define NT 12       // T
#define NNODE 207   // N
#define NF 14       // F
#define NH 128      // H
#define ROWS (NB*NNODE)      // 26496
#define BTN (NB*NT*NNODE)    // 317952
#define G3 (3*NH)            // 384
#define LSTR 208             // padded Laplacian row stride
#define RG (ROWS/16)         // 1656 row-groups of 16

typedef __attribute__((ext_vector_type(8))) short short8;   // 8 bf16 = 4 VGPR
typedef __attribute__((ext_vector_type(4))) float accf4;    // MFMA C/D

#define MFMA16 __builtin_amdgcn_mfma_f32_16x16x32_bf16

__device__ __forceinline__ float sigf(float x){ return 1.0f/(1.0f+__expf(-x)); }
__device__ __forceinline__ unsigned short f2b(float f){
  unsigned int u = __float_as_uint(f);
  return (unsigned short)((u + 0x7FFFu + ((u>>16)&1u)) >> 16);
}
__device__ __forceinline__ float b2f(unsigned short h){
  return __uint_as_float(((unsigned int)h) << 16);
}
// split-bf16 3-term product: hi*hi + lo*hi + hi*lo (lo*lo ~2^-16, negligible)
__device__ __forceinline__ void mm3(short8 ah, short8 al, short8 bh, short8 bl, accf4& acc){
  acc = MFMA16(ah, bh, acc, 0,0,0);
  acc = MFMA16(al, bh, acc, 0,0,0);
  acc = MFMA16(ah, bl, acc, 0,0,0);
}

__global__ __launch_bounds__(256) void k_sentinel(float* __restrict__ out, int n){
  int i = blockIdx.x*256 + threadIdx.x;
  if (i < n) out[i] = 12345.0f;
}

// ---- weight prep (fragment-layout bf16 hi/lo) ----
#define NW_ENC (7*24*64*8)   // 86016
#define NW_DEC (4*24*64*8)   // 49152
#define SH_TOTAL (2*NW_ENC + 2*NW_DEC)
#define FWT_TOTAL (32*384 + 384)
#define PREP_TOTAL (NW_ENC + NW_DEC + 32*384 + 384)
__global__ __launch_bounds__(256) void k_prep(const float* __restrict__ ewih,
    const float* __restrict__ ewhh, const float* __restrict__ dwih,
    const float* __restrict__ dwhh, short* __restrict__ ws, float* __restrict__ wf){
  int i = blockIdx.x*256 + threadIdx.x;
  if (i < NW_ENC){
    int e = i & 7, lane = (i>>3) & 63, ct = (i>>9) % 24, ks = i / 12288;
    int k = ks*32 + (lane>>4)*8 + e;
    int col = ct*16 + (lane&15);
    float wv = (k < 65) ? ewih[col*65 + k] : ((k < 96) ? 0.f : ewhh[col*128 + (k-96)]);
    unsigned short hi = f2b(wv);
    ws[i] = (short)hi;
    ws[NW_ENC + i] = (short)f2b(wv - b2f(hi));
  } else if (i < NW_ENC + NW_DEC){
    int j = i - NW_ENC;
    int e = j & 7, lane = (j>>3) & 63, ct = (j>>9) % 24, ks = j / 12288;
    int k = ks*32 + (lane>>4)*8 + e;
    int col = ct*16 + (lane&15);
    float wv = dwhh[col*128 + k];
    unsigned short hi = f2b(wv);
    ws[2*NW_ENC + j] = (short)hi;
    ws[2*NW_ENC + NW_DEC + j] = (short)f2b(wv - b2f(hi));
  } else if (i < NW_ENC + NW_DEC + 32*384){
    int j = i - (NW_ENC + NW_DEC); int k = j/384, n = j%384;
    wf[j] = dwih[n*33 + 1 + k];
  } else if (i < PREP_TOTAL){
    int n = i - (NW_ENC + NW_DEC + 32*384);
    wf[32*384 + n] = dwih[n*33];
  }
}

// emb = tanh(state * fc_w + fc_b)
__global__ __launch_bounds__(256) void k_emb(const float* __restrict__ x,
    const float* __restrict__ w, const float* __restrict__ b, float* __restrict__ emb){
  int idx = blockIdx.x*256 + threadIdx.x;
  if (idx >= ROWS*16) return;
  int j = idx & 15, row = idx >> 4;
  int bb = row / NNODE, n = row % NNODE;
  float s = x[((bb*NT + (NT-1))*NNODE + n)*NF];
  emb[idx] = tanhf(s*w[j] + b[j]);
}

// wave-per-row adjacency
__global__ __launch_bounds__(256) void k_adj(const float* __restrict__ emb,
    const float* __restrict__ Aph, const float* __restrict__ alp,
    float* __restrict__ Abuf, float* __restrict__ rsum){
  int wid = threadIdx.x >> 6, lane = threadIdx.x & 63;
  int row = blockIdx.x*4 + wid;
  int bb = row / NNODE, n = row % NNODE;
  const float4* er = (const float4*)(emb + (size_t)row*16);
  float4 e0 = er[0], e1 = er[1], e2 = er[2], e3 = er[3];
  float d[4];
  #pragma unroll
  for (int q=0;q<4;++q){
    int m = lane + q*64;
    float dd = -1.f;
    if (m < NNODE){
      const float4* em = (const float4*)(emb + (size_t)(bb*NNODE+m)*16);
      float4 m0 = em[0], m1 = em[1], m2 = em[2], m3 = em[3];
      dd = e0.x*m0.x + e0.y*m0.y + e0.z*m0.z + e0.w*m0.w
         + e1.x*m1.x + e1.y*m1.y + e1.z*m1.z + e1.w*m1.w
         + e2.x*m2.x + e2.y*m2.y + e2.z*m2.z + e2.w*m2.w
         + e3.x*m3.x + e3.y*m3.y + e3.z*m3.z + e3.w*m3.w;
      dd = dd > 0.f ? dd : 0.f;
    }
    d[q] = dd;
  }
  int km = 0;
  float vmax = 0.f;
  for (int it=0; it<10; ++it){
    float v = -1.f; int mi = 1<<20;
    #pragma unroll
    for (int q=0;q<4;++q){
      if (d[q] >= 0.f && !((km>>q)&1) && d[q] > v){ v = d[q]; mi = lane + q*64; }
    }
    #pragma unroll
    for (int off=1; off<64; off<<=1){
      float v2 = __shfl_xor(v, off, 64);
      int  i2 = __shfl_xor(mi, off, 64);
      if (v2 > v || (v2 == v && i2 < mi)){ v = v2; mi = i2; }
    }
    if (it == 0) vmax = v;
    if ((mi & 63) == lane) km |= 1 << (mi >> 6);
  }
  float a = sigf(alp[0]);
  float eneg = __expf(-vmax);
  float p[4]; float ps = 0.f;
  #pragma unroll
  for (int q=0;q<4;++q){
    p[q] = 0.f;
    if (d[q] >= 0.f) p[q] = ((km>>q)&1) ? __expf(d[q]-vmax) : eneg;
    ps += p[q];
  }
  #pragma unroll
  for (int off=1; off<64; off<<=1) ps += __shfl_xor(ps, off, 64);
  float inv = (1.f - a)/ps;
  float rs = 0.f;
  #pragma unroll
  for (int q=0;q<4;++q){
    int m = lane + q*64;
    if (m < NNODE){
      float Av = a*Aph[n*NNODE + m] + p[q]*inv;
      Abuf[(size_t)row*LSTR + m] = Av;
      rs += Av;
    }
  }
  if (lane == 0) Abuf[(size_t)row*LSTR + 207] = 0.f;
  #pragma unroll
  for (int off=1; off<64; off<<=1) rs += __shfl_xor(rs, off, 64);
  if (lane == 0) rsum[row] = rs;
}

__global__ __launch_bounds__(256) void k_lam(const float* __restrict__ rsum, float* __restrict__ lam){
  __shared__ float rv[256];
  int b = blockIdx.x, tid = threadIdx.x;
  rv[tid] = (tid < NNODE) ? rsum[b*NNODE+tid] : -1e30f;
  __syncthreads();
  for (int s=128;s>0;s>>=1){ if (tid<s) rv[tid]=fmaxf(rv[tid],rv[tid+s]); __syncthreads(); }
  if (tid==0) lam[b] = fmaxf(rv[0], 1.0f);
}

__global__ __launch_bounds__(256) void k_lap(float* __restrict__ Abuf, const float* __restrict__ lam){
  int idx = blockIdx.x*256 + threadIdx.x;
  if (idx >= NB*NNODE*LSTR) return;
  int b = idx / (NNODE*LSTR);
  int rem = idx % (NNODE*LSTR);
  int n = rem / LSTR, m = rem % LSTR;
  Abuf[idx] = 2.f*Abuf[idx]/lam[b] - (n==m ? 1.f : 0.f);
}

// causal conv(3) + GLU
__global__ __launch_bounds__(256) void k_tcn(const float* __restrict__ x,
    const float* __restrict__ w, const float* __restrict__ bcn, float* __restrict__ tfeat){
  int idx = blockIdx.x*256 + threadIdx.x;
  if (idx >= BTN*32) return;
  int o = idx & 31; int r = idx >> 5;
  int n = r % NNODE, bt = r / NNODE, t = bt % NT, b = bt / NT;
  float t0 = (t>=2)? x[((size_t)(b*NT+t-2)*NNODE+n)*NF] : 0.f;
  float t1 = (t>=1)? x[((size_t)(b*NT+t-1)*NNODE+n)*NF] : 0.f;
  float t2 = x[((size_t)(b*NT+t)*NNODE+n)*NF];
  float P = bcn[o]    + w[o*3]*t0       + w[o*3+1]*t1       + w[o*3+2]*t2;
  float Q = bcn[o+32] + w[(o+32)*3]*t0  + w[(o+32)*3+1]*t1  + w[(o+32)*3+2]*t2;
  tfeat[(size_t)r*32 + o] = P * sigf(Q);
}

__global__ __launch_bounds__(256) void k_thetaBC(const float* __restrict__ tfeat,
    const float* __restrict__ theta, float* __restrict__ P2, float* __restrict__ P1){
  __shared__ float thB[32][33], thC[32][33];
  __shared__ float tf[8][32];
  int tid = threadIdx.x;
  for (int i=tid; i<1024; i+=256){
    int f = i >> 5, o = i & 31;
    thB[o][f] = theta[1024+f*32+o]; thC[o][f] = theta[2048+f*32+o];
  }
  int rl = tid >> 5, o = tid & 31;
  int r = blockIdx.x*8 + rl;
  tf[rl][o] = tfeat[(size_t)r*32 + o];
  __syncthreads();
  float aB=0.f, aC=0.f;
  #pragma unroll
  for (int f=0; f<32; ++f){
    float t = tf[rl][f];
    aB += t*thB[o][f]; aC += t*thC[o][f];
  }
  int n = r % NNODE, bt = r / NNODE, t = bt % NT, b = bt / NT;
  size_t outi = (size_t)(b*NNODE+n)*G3 + t*32 + o;
  P2[outi]=aB; P1[outi]=aC;
}

__global__ __launch_bounds__(256) void k_thetaA(const float* __restrict__ tfeat,
    const float* __restrict__ theta, float* __restrict__ P1){
  __shared__ float thA[32][33];
  __shared__ float tf[8][32];
  int tid = threadIdx.x;
  for (int i=tid; i<1024; i+=256){
    int f = i >> 5, o = i & 31;
    thA[o][f] = theta[f*32+o] - theta[2048+f*32+o];
  }
  int rl = tid >> 5, o = tid & 31;
  int r = blockIdx.x*8 + rl;
  tf[rl][o] = tfeat[(size_t)r*32 + o];
  __syncthreads();
  float aA=0.f;
  #pragma unroll
  for (int f=0; f<32; ++f) aA += tf[rl][f]*thA[o][f];
  int n = r % NNODE, bt = r / NNODE, t = bt % NT, b = bt / NT;
  P1[(size_t)(b*NNODE+n)*G3 + t*32 + o] = aA;
}

// ---- fp32 128x128 GEMM (Chebyshev + ctxGX) ----
__global__ __launch_bounds__(256) void gemm128(
    const float* __restrict__ Ab, int lda, long long sA,
    const float* __restrict__ Bb, long long sB,
    const float* __restrict__ bias,
    const float* __restrict__ Yb, long long sY, float alphaV, float betaV, int do_relu,
    float* __restrict__ Cb, long long sC, int M, int kchunks){
  __shared__ float As[16][132];
  __shared__ float Bs[16][132];
  int bz = blockIdx.z;
  const float* A = Ab + (size_t)bz*sA;
  const float* B = Bb + (size_t)bz*sB;
  float* C = Cb + (size_t)bz*sC;
  int n0 = blockIdx.x*128, m0 = blockIdx.y*128;
  int tid = threadIdx.x, tx = tid & 15, ty = tid >> 4;
  float acc[8][8] = {};
  int ar = tid & 127, ak = (tid >> 7)*8;
  int bk = tid >> 4, bn = (tid & 15)*8;
  for (int kc=0; kc<kchunks; ++kc){
    int k0 = kc*16;
    int m = m0 + ar;
    if (m < M){
      const float* ap = A + (size_t)m*lda + k0 + ak;
      float4 v0 = *(const float4*)ap, v1 = *(const float4*)(ap+4);
      As[ak+0][ar]=v0.x; As[ak+1][ar]=v0.y; As[ak+2][ar]=v0.z; As[ak+3][ar]=v0.w;
      As[ak+4][ar]=v1.x; As[ak+5][ar]=v1.y; As[ak+6][ar]=v1.z; As[ak+7][ar]=v1.w;
    } else {
      #pragma unroll
      for (int j=0;j<8;++j) As[ak+j][ar]=0.f;
    }
    const float* bp = B + (size_t)(k0+bk)*384 + n0 + bn;
    float4 w0_ = *(const float4*)bp, w1_ = *(const float4*)(bp+4);
    *(float4*)&Bs[bk][bn] = w0_; *(float4*)&Bs[bk][bn+4] = w1_;
    __syncthreads();
    #pragma unroll
    for (int kk=0;kk<16;++kk){
      float4 a0 = *(const float4*)&As[kk][ty*8];
      float4 a1 = *(const float4*)&As[kk][ty*8+4];
      float4 b0 = *(const float4*)&Bs[kk][tx*4];
      float4 b1 = *(const float4*)&Bs[kk][64+tx*4];
      float av[8] = {a0.x,a0.y,a0.z,a0.w,a1.x,a1.y,a1.z,a1.w};
      float bv[8] = {b0.x,b0.y,b0.z,b0.w,b1.x,b1.y,b1.z,b1.w};
      #pragma unroll
      for (int i=0;i<8;++i)
        #pragma unroll
        for (int j=0;j<8;++j) acc[i][j] += av[i]*bv[j];
    }
    __syncthreads();
  }
  if (bias){
    float bl[4], bh_[4];
    #pragma unroll
    for (int j=0;j<4;++j){ bl[j]=bias[n0+tx*4+j]; bh_[j]=bias[n0+64+tx*4+j]; }
    #pragma unroll
    for (int i=0;i<8;++i){
      int m2 = m0 + ty*8 + i; if (m2 >= M) continue;
      float4 s0, s1;
      s0.x=acc[i][0]+bl[0]; s0.y=acc[i][1]+bl[1]; s0.z=acc[i][2]+bl[2]; s0.w=acc[i][3]+bl[3];
      s1.x=acc[i][4]+bh_[0]; s1.y=acc[i][5]+bh_[1]; s1.z=acc[i][6]+bh_[2]; s1.w=acc[i][7]+bh_[3];
      *(float4*)&C[(size_t)m2*384 + n0 + tx*4] = s0;
      *(float4*)&C[(size_t)m2*384 + n0 + 64 + tx*4] = s1;
    }
  } else {
    const float* Y = Yb + (size_t)bz*sY;
    #pragma unroll
    for (int i=0;i<8;++i){
      int m2 = m0 + ty*8 + i; if (m2 >= M) continue;
      const float* yr = Y + (size_t)m2*384;
      float* cr = C + (size_t)m2*384;
      float4 y0 = *(const float4*)(yr + n0 + tx*4);
      float4 y1 = *(const float4*)(yr + n0 + 64 + tx*4);
      float4 s0, s1;
      s0.x = alphaV*acc[i][0] + betaV*y0.x; s0.y = alphaV*acc[i][1] + betaV*y0.y;
      s0.z = alphaV*acc[i][2] + betaV*y0.z; s0.w = alphaV*acc[i][3] + betaV*y0.w;
      s1.x = alphaV*acc[i][4] + betaV*y1.x; s1.y = alphaV*acc[i][5] + betaV*y1.y;
      s1.z = alphaV*acc[i][6] + betaV*y1.z; s1.w = alphaV*acc[i][7] + betaV*y1.w;
      if (do_relu){
        s0.x=fmaxf(s0.x,0.f); s0.y=fmaxf(s0.y,0.f); s0.z=fmaxf(s0.z,0.f); s0.w=fmaxf(s0.w,0.f);
        s1.x=fmaxf(s1.x,0.f); s1.y=fmaxf(s1.y,0.f); s1.z=fmaxf(s1.z,0.f); s1.w=fmaxf(s1.w,0.f);
      }
      *(float4*)(cr + n0 + tx*4) = s0;
      *(float4*)(cr + n0 + 64 + tx*4) = s1;
    }
  }
}

// ===================== persistent MFMA encoder+decoder (v5) =====================
// 16 rows/block (grid 1656), 512 threads (8 waves). Wave w owns h-cols [16w,16w+16).
// z pre-split in A-frag layout (global); h in fp32 regs + split A-frag LDS copy.
// 2 barriers per step; zero in-loop staging; 4 blocks/CU resident.
#define GATEB(WH, WL, KS) \
    const int ko = (KS)*24; \
    short8 bRh = *(const short8*)(WH + ((size_t)(ko + w)*64 + lane)*8); \
    short8 bZh = *(const short8*)(WH + ((size_t)(ko + 8 + w)*64 + lane)*8); \
    short8 bNh = *(const short8*)(WH + ((size_t)(ko + 16 + w)*64 + lane)*8); \
    short8 bRl = *(const short8*)(WL + ((size_t)(ko + w)*64 + lane)*8); \
    short8 bZl = *(const short8*)(WL + ((size_t)(ko + 8 + w)*64 + lane)*8); \
    short8 bNl = *(const short8*)(WL + ((size_t)(ko + 16 + w)*64 + lane)*8);

__global__ __launch_bounds__(512) void k_encdec(
    const short* __restrict__ zfH, const short* __restrict__ zfL,
    const short* __restrict__ WFH, const short* __restrict__ WFL,
    const float* __restrict__ bih, const float* __restrict__ bhh,
    const short* __restrict__ DFH, const short* __restrict__ DFL,
    const float* __restrict__ dbhh, const float* __restrict__ ctxGX,
    const float* __restrict__ w0, const float* __restrict__ ow,
    const float* __restrict__ ob, const float* __restrict__ pred0,
    float* __restrict__ preds_out){
  __shared__ __attribute__((aligned(16))) short hfH[4*512];   // [ks][lane*8+e]
  __shared__ __attribute__((aligned(16))) short hfL[4*512];
  __shared__ float psl[8][16];
  __shared__ float predl[16];
  int R = blockIdx.x, m0 = R*16;
  int tid = threadIdx.x;
  int w = tid >> 6, lane = tid & 63;
  int g = lane >> 4, c = lane & 15;
  int j = (w<<4) + c;
  float hreg[4] = {};
  for (int i = tid; i < 2048; i += 512){ hfH[i] = 0; hfL[i] = 0; }
  if (tid < 16) predl[tid] = pred0[m0 + tid];
  // epilogue write coords: h element (row, j) -> frag (ks_h, lane', e)
  int ksh = w >> 1, qh = 2*(w&1) + (c>>3), eh = c & 7;
  float birv = bih[j], bizv = bih[128+j], binv = bih[256+j];
  float bhrv = bhh[j], bhzv = bhh[128+j], bhnv = bhh[256+j];
  __syncthreads();

  // -------- encoder: 12 steps --------
  for (int t = 0; t < NT; ++t){
    accf4 aR = {}, aZ = {}, aNZ = {}, aNH = {};
    #pragma unroll
    for (int ks=0; ks<3; ++ks){
      GATEB(WFH, WFL, ks);
      size_t zb = (((size_t)t*RG + R)*3 + ks)*512;
      short8 ah = *(const short8*)(zfH + zb + lane*8);
      short8 al = *(const short8*)(zfL + zb + lane*8);
      mm3(ah, al, bRh, bRl, aR);
      mm3(ah, al, bZh, bZl, aZ);
      mm3(ah, al, bNh, bNl, aNZ);
    }
    #pragma unroll
    for (int ks=3; ks<7; ++ks){
      GATEB(WFH, WFL, ks);
      short8 ah = *(const short8*)&hfH[(ks-3)*512 + lane*8];
      short8 al = *(const short8*)&hfL[(ks-3)*512 + lane*8];
      mm3(ah, al, bRh, bRl, aR);
      mm3(ah, al, bZh, bZl, aZ);
      mm3(ah, al, bNh, bNl, aNH);
    }
    __syncthreads();   // all hf reads done
    #pragma unroll
    for (int i=0;i<4;++i){
      float r_ = sigf(aR[i] + birv + bhrv);
      float z_ = sigf(aZ[i] + bizv + bhzv);
      float n_ = tanhf(aNZ[i] + binv + r_*(aNH[i] + bhnv));
      float hn = (1.f - z_)*n_ + z_*hreg[i];
      hreg[i] = hn;
      unsigned short hh = f2b(hn);
      int o = ksh*512 + ((g*4+i) + 16*qh)*8 + eh;
      hfH[o] = (short)hh;
      hfL[o] = (short)f2b(hn - b2f(hh));
    }
    __syncthreads();   // hf writes visible
  }

  // -------- decoder: 12 steps --------
  float w0r = w0[j], w0z = w0[128+j], w0n = w0[256+j];
  float bhr = dbhh[j], bhz = dbhh[128+j], bhn = dbhh[256+j];
  float owj = ow[j];
  float obv = ob[0];
  for (int s = 0; s < NT; ++s){
    accf4 aR = {}, aZ = {}, aN = {};
    #pragma unroll
    for (int ks=0; ks<4; ++ks){
      GATEB(DFH, DFL, ks);
      short8 ah = *(const short8*)&hfH[ks*512 + lane*8];
      short8 al = *(const short8*)&hfL[ks*512 + lane*8];
      mm3(ah, al, bRh, bRl, aR);
      mm3(ah, al, bZh, bZl, aZ);
      mm3(ah, al, bNh, bNl, aN);
    }
    __syncthreads();   // hf reads done; predl from prev step visible
    #pragma unroll
    for (int i=0;i<4;++i){
      int row = g*4 + i;
      float p = predl[row];
      const float* gx = ctxGX + (size_t)(m0+row)*384;
      float r_ = sigf(gx[j]     + p*w0r + aR[i] + bhr);
      float z_ = sigf(gx[128+j] + p*w0z + aZ[i] + bhz);
      float n_ = tanhf(gx[256+j] + p*w0n + r_*(aN[i] + bhn));
      float hn = (1.f - z_)*n_ + z_*hreg[i];
      hreg[i] = hn;
      unsigned short hh = f2b(hn);
      int o = ksh*512 + (row + 16*qh)*8 + eh;
      hfH[o] = (short)hh;
      hfL[o] = (short)f2b(hn - b2f(hh));
      float psv = hn*owj;
      psv += __shfl_xor(psv, 1, 64);
      psv += __shfl_xor(psv, 2, 64);
      psv += __shfl_xor(psv, 4, 64);
      psv += __shfl_xor(psv, 8, 64);
      if (c == 0) psl[w][row] = psv;
    }
    __syncthreads();   // hf + psl writes visible
    if (tid < 16){
      float sm = obv;
      #pragma unroll
      for (int w2=0; w2<8; ++w2) sm += psl[w2][tid];
      predl[tid] = sm;
      preds_out[(size_t)s*ROWS + m0 + tid] = sm;
    }
    // predl consumed after next GATE's __syncthreads -> safe
  }
}

// fusion + attn gate; writes z pre-split into MFMA A-frag layout (zfH/zfL)
__global__ __launch_bounds__(256) void k_zbuild(const float* __restrict__ x,
    const float* __restrict__ S, const float* __restrict__ cw, const float* __restrict__ cb,
    const float* __restrict__ aw, const float* __restrict__ ab,
    short* __restrict__ zfH, short* __restrict__ zfL,
    float* __restrict__ ctx, float* __restrict__ pred0){
  __shared__ float cwl[416];
  __shared__ float cbl[32];
  __shared__ float awl[65];
  int tid = threadIdx.x;
  for (int i=tid; i<416; i+=256) cwl[i] = cw[i];
  if (tid < 32) cbl[tid] = cb[tid];
  if (tid < 65) awl[tid] = aw[tid];
  __syncthreads();
  int wid = tid >> 6, sel = (tid >> 5) & 1, hl = tid & 31;
  int r = blockIdx.x*8 + wid*2 + sel;
  int n = r % NNODE, bt = r / NNODE, t = bt % NT, b = bt / NT;
  const float* xr = x + (size_t)r*NF;
  float x0 = xr[0];
  float s_ = cbl[hl];
  #pragma unroll
  for (int f=0; f<13; ++f) s_ += xr[1+f]*cwl[hl*13+f];
  float ce = s_ > 0.f ? s_ : 0.f;
  float sv = S[(size_t)(b*NNODE+n)*G3 + t*32 + hl];
  float part = sv*awl[1+hl] + ce*awl[33+hl] + (hl==0 ? x0*awl[0] : 0.f);
  part += __shfl_xor(part, 1, 64);
  part += __shfl_xor(part, 2, 64);
  part += __shfl_xor(part, 4, 64);
  part += __shfl_xor(part, 8, 64);
  part += __shfl_xor(part, 16, 64);
  float attn = sigf(part + ab[0]);
  int i_ = r / NT, tau = r % NT;          // scrambled reshape (B*N, T, 65)
  int Rg = i_ >> 4, rowin = i_ & 15;
  size_t basez = (((size_t)tau*RG + Rg)*3)*512;
  #define ZPUT(L, V) do{ int l_=(L); int ks_=l_>>5, q_=(l_&31)>>3, e_=l_&7; \
      size_t o_ = basez + (size_t)ks_*512 + ((rowin + 16*q_)<<3) + e_; \
      float v_=(V); unsigned short hh_ = f2b(v_); \
      zfH[o_] = (short)hh_; zfL[o_] = (short)f2b(v_ - b2f(hh_)); }while(0)
  ZPUT(1+hl, sv*attn);
  ZPUT(33+hl, ce*attn);
  if (hl == 0) ZPUT(0, x0*attn);
  if (hl <= 30) ZPUT(65+hl, 0.f);   // pad l=65..95
  #undef ZPUT
  if (t == NT-1){
    ctx[(size_t)(b*NNODE+n)*32 + hl] = ce;
    if (hl == 0) pred0[b*NNODE+n] = x0;
  }
}

__global__ __launch_bounds__(256) void k_out(const float* __restrict__ preds, float* __restrict__ out){
  int idx = blockIdx.x*256 + threadIdx.x;
  if (idx >= NT*ROWS) return;
  int n = idx % NNODE;
  int t2 = idx / NNODE;
  int hor = t2 % NT;
  int b = t2 / NT;
  out[idx] = preds[(size_t)hor*ROWS + b*NNODE + n];
}

extern "C" void kernel_launch(void* const* d_in, const int* in_sizes, int n_in,
                              void* d_out, int out_size, void* d_ws, size_t ws_size,
                              hipStream_t stream){
  const float* x     = (const float*)d_in[0];
  const float* Aph   = (const float*)d_in[1];
  const float* fcw   = (const float*)d_in[2];
  const float* fcb   = (const float*)d_in[3];
  const float* alp   = (const float*)d_in[4];
  const float* cw    = (const float*)d_in[5];
  const float* cb    = (const float*)d_in[6];
  const float* tw    = (const float*)d_in[7];
  const float* tb    = (const float*)d_in[8];
  const float* theta = (const float*)d_in[9];
  const float* aw    = (const float*)d_in[10];
  const float* ab    = (const float*)d_in[11];
  const float* ewih  = (const float*)d_in[12];
  const float* ewhh  = (const float*)d_in[13];
  const float* ebih  = (const float*)d_in[14];
  const float* ebhh  = (const float*)d_in[15];
  const float* dwih  = (const float*)d_in[16];
  const float* dwhh  = (const float*)d_in[17];
  const float* dbih  = (const float*)d_in[18];
  const float* dbhh  = (const float*)d_in[19];
  const float* ow    = (const float*)d_in[20];
  const float* ob    = (const float*)d_in[21];
  float* out = (float*)d_out;

  const size_t SZ_CTX  = (size_t)ROWS*32;
  const size_t SZ_PRED = (size_t)ROWS;
  const size_t SZ_PREDS= (size_t)NT*ROWS;
  const size_t SZ_G    = (size_t)ROWS*G3;
  const size_t SZ_ABUF = (size_t)NB*NNODE*LSTR;
  const size_t SZ_EMB  = (size_t)ROWS*16;
  const size_t SZ_ZF   = (size_t)NT*RG*3*512;           // shorts per array
  const size_t SZ_UNION_FL = (2*SZ_ZF + 3) / 2;          // zfH+zfL in floats
  const size_t UNION_FL = (SZ_UNION_FL > 2*SZ_G) ? SZ_UNION_FL : 2*SZ_G;

  float* w = (float*)d_ws;
  size_t off = 0;
  auto alloc = [&](size_t nfl){ float* p = w + off; off += nfl; return p; };
  float* ctx   = alloc(SZ_CTX);
  float* pred  = alloc(SZ_PRED);
  float* preds = alloc(SZ_PREDS);
  float* Abuf  = alloc(SZ_ABUF);
  float* emb   = alloc(SZ_EMB);
  float* rsum  = alloc(SZ_PRED);
  float* lam   = alloc((size_t)NB);
  short* wS    = (short*)alloc(SH_TOTAL/2);
  float* wF    = alloc((size_t)FWT_TOTAL);
  float* Sslot = alloc(SZ_G);      // t_feat -> S -> ctxGX
  float* Uzone = alloc(UNION_FL);  // P1 | P2 during Chebyshev; zfH|zfL after
  float* P1 = Uzone;
  float* P2 = Uzone + SZ_G;
  short* zfH = (short*)Uzone;
  short* zfL = zfH + SZ_ZF;
  (void)n_in; (void)in_sizes;

  if (ws_size < off*sizeof(float)){    // tripwire: workspace too small
    k_sentinel<<<(out_size+255)/256, 256, 0, stream>>>(out, out_size);
    return;
  }

  const short* WFH = wS;
  const short* WFL = wS + NW_ENC;
  const short* DFH = wS + 2*NW_ENC;
  const short* DFL = wS + 2*NW_ENC + NW_DEC;
  float* dwihT = wF;
  float* w0    = wF + 32*384;

  k_prep<<<(PREP_TOTAL+255)/256, 256, 0, stream>>>(ewih, ewhh, dwih, dwhh, wS, wF);
  float* tfeat = Sslot;
  k_emb<<<(ROWS*16)/256, 256, 0, stream>>>(x, fcw, fcb, emb);
  k_adj<<<ROWS/4, 256, 0, stream>>>(emb, Aph, alp, Abuf, rsum);
  k_lam<<<NB, 256, 0, stream>>>(rsum, lam);
  k_lap<<<(NB*NNODE*LSTR)/256, 256, 0, stream>>>(Abuf, lam);
  k_tcn<<<(BTN*32)/256, 256, 0, stream>>>(x, tw, tb, tfeat);
  k_thetaBC<<<BTN/8, 256, 0, stream>>>(tfeat, theta, P2, P1);
  // P2 <- 2*(L @ P1) + P2
  gemm128<<<dim3(3, 2, NB), 256, 0, stream>>>(Abuf, LSTR, (long long)NNODE*LSTR,
      P1, (long long)NNODE*G3, nullptr,
      P2, (long long)NNODE*G3, 2.f, 1.f, 0,
      P2, (long long)NNODE*G3, NNODE, 13);
  k_thetaA<<<BTN/8, 256, 0, stream>>>(tfeat, theta, P1);
  // Sslot <- relu((L @ P2) + P1)
  gemm128<<<dim3(3, 2, NB), 256, 0, stream>>>(Abuf, LSTR, (long long)NNODE*LSTR,
      P2, (long long)NNODE*G3, nullptr,
      P1, (long long)NNODE*G3, 1.f, 1.f, 1,
      Sslot, (long long)NNODE*G3, NNODE, 13);
  k_zbuild<<<BTN/8, 256, 0, stream>>>(x, Sslot, cw, cb, aw, ab, zfH, zfL, ctx, pred);
  float* ctxGX = Sslot;  // S dead after zbuild
  gemm128<<<dim3(3, ROWS/128, 1), 256, 0, stream>>>(
      ctx, 32, 0, dwihT, 0, dbih,
      nullptr, 0, 1.f, 0.f, 0, ctxGX, 0, ROWS, 2);
  k_encdec<<<RG, 512, 0, stream>>>(zfH, zfL, WFH, WFL, ebih, ebhh,
      DFH, DFL, dbhh, ctxGX, w0, ow, ob, pred, preds);
  k_out<<<(NT*ROWS)/256, 256, 0, stream>>>(preds, out);
}